// Round 3
// baseline (457.316 us; speedup 1.0000x reference)
//
#include <hip/hip_runtime.h>
#include <hip/hip_bf16.h>

// Problem: B=2, S=2048, H=1024, HEADS=16, HEAD_DIM=64.
// Wire dtype CONFIRMED fp32 (round-1 NaN = fp32-as-bf16 poisoning; round-2
// even-column-zero signature = sniff failing on ln_g ones). Output fp32.
#define SEQ     2048
#define BATCH   2
#define HID     1024
#define NHEADS  16
#define HD      64
#define MTOT    4096            // BATCH*SEQ
#define LNEPS   1e-6f
#define L2E     1.4426950408889634f

typedef __bf16 bf16_t;
typedef bf16_t bf16x8 __attribute__((ext_vector_type(8)));   // 4 VGPRs = one MFMA A/B frag
typedef float  floatx4 __attribute__((ext_vector_type(4)));  // one MFMA C/D frag

__device__ __forceinline__ floatx4 mfma16(bf16x8 a, bf16x8 b, floatx4 c) {
    return __builtin_amdgcn_mfma_f32_16x16x32_bf16(a, b, c, 0, 0, 0);
}
__device__ __forceinline__ bf16x8 ldg8(const bf16_t* p) { return *(const bf16x8*)p; }

// ---------------------------------------------------------------------------
// Kernel 0: fp32 -> bf16 conversion for X, Wq, Wk, Wv, Wo.
// ---------------------------------------------------------------------------
__global__ __launch_bounds__(256) void cvt_kernel(
    const float* sX, const float* sWq, const float* sWk, const float* sWv, const float* sWo,
    bf16_t* dX, bf16_t* dWq, bf16_t* dWk, bf16_t* dWv, bf16_t* dWo)
{
    const int z = blockIdx.z;
    const float* src; bf16_t* dst; int n;
    switch (z) {
        case 0:  src = sX;  dst = dX;  n = MTOT * HID; break;
        case 1:  src = sWq; dst = dWq; n = HID * HID;  break;
        case 2:  src = sWk; dst = dWk; n = HID * HID;  break;
        case 3:  src = sWv; dst = dWv; n = HID * HID;  break;
        default: src = sWo; dst = dWo; n = HID * HID;  break;
    }
    const int n4 = n >> 2;
    const int stride = gridDim.x * blockDim.x;
    for (int i = blockIdx.x * blockDim.x + threadIdx.x; i < n4; i += stride) {
        const float4 v = ((const float4*)src)[i];
        bf16_t o[4] = {(bf16_t)v.x, (bf16_t)v.y, (bf16_t)v.z, (bf16_t)v.w};
        *(unsigned long long*)(dst + 4 * i) = *(unsigned long long*)o;
    }
}

// ---------------------------------------------------------------------------
// Kernel 1: QKV projection.  C[m,n] = sum_k X[m,k]*W[n,k] + b[n]  (NT GEMM)
// Store into [b, h, s, d] bf16. Block = 4 waves (2x2), block tile 128x128,
// wave tile 64x64 (4x4 MFMA). Fragments loaded directly from global.
// ---------------------------------------------------------------------------
__global__ __launch_bounds__(256) void qkv_kernel(
    const bf16_t* __restrict__ X,
    const bf16_t* __restrict__ Wq, const float* __restrict__ bq,
    const bf16_t* __restrict__ Wk, const float* __restrict__ bk,
    const bf16_t* __restrict__ Wv, const float* __restrict__ bv,
    bf16_t* __restrict__ Qo, bf16_t* __restrict__ Ko, bf16_t* __restrict__ Vo)
{
    const int z = blockIdx.z;
    const bf16_t* W    = (z == 0) ? Wq : (z == 1) ? Wk : Wv;
    const float*  bias = (z == 0) ? bq : (z == 1) ? bk : bv;
    bf16_t*       out  = (z == 0) ? Qo : (z == 1) ? Ko : Vo;

    const int lane = threadIdx.x & 63;
    const int wave = threadIdx.x >> 6;
    const int l16  = lane & 15;
    const int quad = lane >> 4;
    const int m_base = blockIdx.y * 128 + (wave >> 1) * 64;
    const int n_base = blockIdx.x * 128 + (wave & 1) * 64;

    floatx4 acc[4][4];
#pragma unroll
    for (int i = 0; i < 4; i++)
#pragma unroll
        for (int j = 0; j < 4; j++) acc[i][j] = (floatx4)0.0f;

    for (int k0 = 0; k0 < HID; k0 += 32) {
        const int kk = k0 + quad * 8;
        bf16x8 a[4], b[4];
#pragma unroll
        for (int i = 0; i < 4; i++) a[i] = ldg8(X + (size_t)(m_base + i * 16 + l16) * HID + kk);
#pragma unroll
        for (int j = 0; j < 4; j++) b[j] = ldg8(W + (size_t)(n_base + j * 16 + l16) * HID + kk);
#pragma unroll
        for (int i = 0; i < 4; i++)
#pragma unroll
            for (int j = 0; j < 4; j++) acc[i][j] = mfma16(a[i], b[j], acc[i][j]);
    }

    float bv_[4];
#pragma unroll
    for (int j = 0; j < 4; j++) bv_[j] = bias[n_base + j * 16 + l16];

#pragma unroll
    for (int i = 0; i < 4; i++) {
#pragma unroll
        for (int j = 0; j < 4; j++) {
            const int n = n_base + j * 16 + l16;
            const int h = n >> 6, d = n & 63;
#pragma unroll
            for (int r = 0; r < 4; r++) {
                const int m = m_base + i * 16 + quad * 4 + r;   // C layout: row=quad*4+r, col=l16
                const int bb = m >> 11, s = m & (SEQ - 1);
                out[(((size_t)(bb * NHEADS + h)) * SEQ + s) * HD + d] = (bf16_t)(acc[i][j][r] + bv_[j]);
            }
        }
    }
}

// ---------------------------------------------------------------------------
// Kernel 2: flash attention per (b,h).  Block = 4 waves; wave owns 16 q-rows.
// kv in tiles of 32; K tile + transposed V tile staged in LDS.
// ---------------------------------------------------------------------------
__global__ __launch_bounds__(256) void attn_kernel(
    const bf16_t* __restrict__ Q, const bf16_t* __restrict__ K,
    const bf16_t* __restrict__ V, const int* __restrict__ mask,
    bf16_t* __restrict__ ctx)
{
    const int bh = blockIdx.y;            // 0..31
    const int b  = bh >> 4;
    const int h  = bh & 15;
    const int lane = threadIdx.x & 63;
    const int wave = threadIdx.x >> 6;
    const int l16  = lane & 15;
    const int quad = lane >> 4;

    const bf16_t* Qh = Q + (size_t)bh * SEQ * HD;
    const bf16_t* Kh = K + (size_t)bh * SEQ * HD;
    const bf16_t* Vh = V + (size_t)bh * SEQ * HD;

    __shared__ __align__(16) bf16_t Kt[32 * 72];
    __shared__ __align__(16) bf16_t Vt[64 * 40];      // transposed: Vt[d][k]
    __shared__ __align__(16) bf16_t Pl[4 * 16 * 40];  // per-wave P tile [16 q][32 kv]

    const int q0 = blockIdx.x * 64 + wave * 16;

    bf16x8 aQ[2];
    aQ[0] = ldg8(Qh + (size_t)(q0 + l16) * HD + quad * 8);        // A frag: m=l16, k=quad*8+j
    aQ[1] = ldg8(Qh + (size_t)(q0 + l16) * HD + 32 + quad * 8);

    floatx4 O[4];
    float mi[4], li[4];
#pragma unroll
    for (int r = 0; r < 4; r++) { O[r] = (floatx4)0.0f; mi[r] = -1.0e30f; li[r] = 0.0f; }

    const int t = threadIdx.x;
    const int ldrow = t >> 3;         // 0..31 (kv row within tile)
    const int ldcol = (t & 7) * 8;    // 0..56 (d col)

    bf16_t* Pw = Pl + wave * (16 * 40);

    for (int kt = 0; kt < SEQ; kt += 32) {
        __syncthreads();
        bf16x8 krow = ldg8(Kh + (size_t)(kt + ldrow) * HD + ldcol);
        *(bf16x8*)&Kt[ldrow * 72 + ldcol] = krow;
        bf16x8 vrow = ldg8(Vh + (size_t)(kt + ldrow) * HD + ldcol);
#pragma unroll
        for (int j = 0; j < 8; j++) Vt[(ldcol + j) * 40 + ldrow] = vrow[j];
        __syncthreads();

        floatx4 sc[2];
#pragma unroll
        for (int ct = 0; ct < 2; ct++) {
            floatx4 s = (floatx4)0.0f;
#pragma unroll
            for (int c = 0; c < 2; c++) {
                bf16x8 bK = *(const bf16x8*)&Kt[(ct * 16 + l16) * 72 + c * 32 + quad * 8];
                s = mfma16(aQ[c], bK, s);
            }
            const int mv = mask[b * SEQ + kt + ct * 16 + l16];
            const float biasv = mv ? 0.0f : -1.0e30f;
#pragma unroll
            for (int r = 0; r < 4; r++) s[r] = s[r] * 0.125f + biasv;
            sc[ct] = s;
        }

        float mnew[4], alpha[4], psum[4];
#pragma unroll
        for (int r = 0; r < 4; r++) {
            float mx = fmaxf(sc[0][r], sc[1][r]);
#pragma unroll
            for (int off = 1; off < 16; off <<= 1) mx = fmaxf(mx, __shfl_xor(mx, off, 64));
            mnew[r] = fmaxf(mi[r], mx);
            alpha[r] = exp2f((mi[r] - mnew[r]) * L2E);
        }
#pragma unroll
        for (int r = 0; r < 4; r++) {
            float p0 = exp2f((sc[0][r] - mnew[r]) * L2E);
            float p1 = exp2f((sc[1][r] - mnew[r]) * L2E);
            sc[0][r] = p0; sc[1][r] = p1;
            float su = p0 + p1;
#pragma unroll
            for (int off = 1; off < 16; off <<= 1) su += __shfl_xor(su, off, 64);
            psum[r] = su;
        }
#pragma unroll
        for (int r = 0; r < 4; r++) { li[r] = li[r] * alpha[r] + psum[r]; mi[r] = mnew[r]; }
#pragma unroll
        for (int nb = 0; nb < 4; nb++)
#pragma unroll
            for (int r = 0; r < 4; r++) O[nb][r] *= alpha[r];

        // P: C layout -> LDS -> A layout (same-wave DS ops are in-order)
#pragma unroll
        for (int ct = 0; ct < 2; ct++)
#pragma unroll
            for (int r = 0; r < 4; r++)
                Pw[(quad * 4 + r) * 40 + ct * 16 + l16] = (bf16_t)sc[ct][r];
        bf16x8 aP = *(const bf16x8*)&Pw[l16 * 40 + quad * 8];

#pragma unroll
        for (int nb = 0; nb < 4; nb++) {
            bf16x8 bV = *(const bf16x8*)&Vt[(nb * 16 + l16) * 40 + quad * 8];
            O[nb] = mfma16(aP, bV, O[nb]);
        }
    }

    float inv[4];
#pragma unroll
    for (int r = 0; r < 4; r++) inv[r] = (li[r] > 0.0f) ? 1.0f / li[r] : 0.0f;
#pragma unroll
    for (int nb = 0; nb < 4; nb++) {
#pragma unroll
        for (int r = 0; r < 4; r++) {
            const int s = q0 + quad * 4 + r;
            const int d = h * HD + nb * 16 + l16;
            ctx[((size_t)(b * SEQ + s)) * HID + d] = (bf16_t)(O[nb][r] * inv[r]);
        }
    }
}

// ---------------------------------------------------------------------------
// Kernel 3: res = ctx @ Wo^T + bo + hidden  -> fp32
// ---------------------------------------------------------------------------
__global__ __launch_bounds__(256) void oproj_kernel(
    const bf16_t* __restrict__ C, const bf16_t* __restrict__ Wo,
    const float* __restrict__ bo, const float* __restrict__ X,
    float* __restrict__ res)
{
    const int lane = threadIdx.x & 63;
    const int wave = threadIdx.x >> 6;
    const int l16  = lane & 15;
    const int quad = lane >> 4;
    const int m_base = blockIdx.y * 128 + (wave >> 1) * 64;
    const int n_base = blockIdx.x * 128 + (wave & 1) * 64;

    floatx4 acc[4][4];
#pragma unroll
    for (int i = 0; i < 4; i++)
#pragma unroll
        for (int j = 0; j < 4; j++) acc[i][j] = (floatx4)0.0f;

    for (int k0 = 0; k0 < HID; k0 += 32) {
        const int kk = k0 + quad * 8;
        bf16x8 a[4], b[4];
#pragma unroll
        for (int i = 0; i < 4; i++) a[i] = ldg8(C + (size_t)(m_base + i * 16 + l16) * HID + kk);
#pragma unroll
        for (int j = 0; j < 4; j++) b[j] = ldg8(Wo + (size_t)(n_base + j * 16 + l16) * HID + kk);
#pragma unroll
        for (int i = 0; i < 4; i++)
#pragma unroll
            for (int j = 0; j < 4; j++) acc[i][j] = mfma16(a[i], b[j], acc[i][j]);
    }

    float bv_[4];
#pragma unroll
    for (int j = 0; j < 4; j++) bv_[j] = bo[n_base + j * 16 + l16];

#pragma unroll
    for (int i = 0; i < 4; i++) {
#pragma unroll
        for (int j = 0; j < 4; j++) {
            const int n = n_base + j * 16 + l16;
#pragma unroll
            for (int r = 0; r < 4; r++) {
                const int m = m_base + i * 16 + quad * 4 + r;
                res[(size_t)m * HID + n] = acc[i][j][r] + bv_[j] + X[(size_t)m * HID + n];
            }
        }
    }
}

// ---------------------------------------------------------------------------
// Kernel 4: LayerNorm over rows of 1024 fp32 -> fp32 out
// ---------------------------------------------------------------------------
__global__ __launch_bounds__(256) void ln_kernel(
    const float* __restrict__ res, const float* __restrict__ g,
    const float* __restrict__ be, float* __restrict__ out)
{
    __shared__ float red1[4], red2[4];
    const int row  = blockIdx.x;
    const int lane = threadIdx.x & 63;
    const int wave = threadIdx.x >> 6;
    const float4 v = ((const float4*)(res + (size_t)row * HID))[threadIdx.x];

    float s = v.x + v.y + v.z + v.w;
#pragma unroll
    for (int off = 1; off < 64; off <<= 1) s += __shfl_xor(s, off, 64);
    if (lane == 0) red1[wave] = s;
    __syncthreads();
    const float mu = (red1[0] + red1[1] + red1[2] + red1[3]) * (1.0f / HID);

    const float d0 = v.x - mu, d1 = v.y - mu, d2 = v.z - mu, d3 = v.w - mu;
    float ss = d0 * d0 + d1 * d1 + d2 * d2 + d3 * d3;
#pragma unroll
    for (int off = 1; off < 64; off <<= 1) ss += __shfl_xor(ss, off, 64);
    if (lane == 0) red2[wave] = ss;
    __syncthreads();
    const float var = (red2[0] + red2[1] + red2[2] + red2[3]) * (1.0f / HID);
    const float rstd = rsqrtf(var + LNEPS);

    const int col = threadIdx.x * 4;
    const float4 gv = ((const float4*)g)[threadIdx.x];
    const float4 bv = ((const float4*)be)[threadIdx.x];
    float4 o;
    o.x = d0 * rstd * gv.x + bv.x;
    o.y = d1 * rstd * gv.y + bv.y;
    o.z = d2 * rstd * gv.z + bv.z;
    o.w = d3 * rstd * gv.w + bv.w;
    ((float4*)(out + (size_t)row * HID))[threadIdx.x] = o;
    (void)col;
}

// ---------------------------------------------------------------------------
extern "C" void kernel_launch(void* const* d_in, const int* in_sizes, int n_in,
                              void* d_out, int out_size, void* d_ws, size_t ws_size,
                              hipStream_t stream)
{
    const float* X  = (const float*)d_in[0];
    const int* mask = (const int*)d_in[1];
    const float* Wq = (const float*)d_in[2];  const float* bq = (const float*)d_in[3];
    const float* Wk = (const float*)d_in[4];  const float* bk = (const float*)d_in[5];
    const float* Wv = (const float*)d_in[6];  const float* bv = (const float*)d_in[7];
    const float* Wo = (const float*)d_in[8];  const float* bo = (const float*)d_in[9];
    const float* g  = (const float*)d_in[10]; const float* be = (const float*)d_in[11];
    float* out = (float*)d_out;

    char* ws = (char*)d_ws;
    bf16_t* Qb  = (bf16_t*)(ws);                          // [0, 8M)
    bf16_t* Kb  = (bf16_t*)(ws + (8ull  << 20));          // [8M, 16M)
    bf16_t* Vb  = (bf16_t*)(ws + (16ull << 20));          // [16M, 24M)
    bf16_t* Cb  = (bf16_t*)(ws + (24ull << 20));          // [24M, 32M)
    float*  Rb  = (float*)(ws);                           // [0, 16M) aliases dead Q/K
    bf16_t* Xc  = (bf16_t*)(ws + (32ull << 20));          // [32M, 40M)
    bf16_t* Wqc = (bf16_t*)(ws + (40ull << 20));
    bf16_t* Wkc = (bf16_t*)(ws + (42ull << 20));
    bf16_t* Wvc = (bf16_t*)(ws + (44ull << 20));
    bf16_t* Woc = (bf16_t*)(ws + (46ull << 20));

    cvt_kernel <<<dim3(128, 1, 5), 256, 0, stream>>>(X, Wq, Wk, Wv, Wo, Xc, Wqc, Wkc, Wvc, Woc);
    qkv_kernel <<<dim3(8, 32, 3), 256, 0, stream>>>(Xc, Wqc, bq, Wkc, bk, Wvc, bv, Qb, Kb, Vb);
    attn_kernel<<<dim3(SEQ / 64, BATCH * NHEADS), 256, 0, stream>>>(Qb, Kb, Vb, mask, Cb);
    oproj_kernel<<<dim3(8, 32), 256, 0, stream>>>(Cb, Woc, bo, X, Rb);
    ln_kernel  <<<MTOT, 256, 0, stream>>>(Rb, g, be, out);
}

// Round 4
// 368.927 us; speedup vs baseline: 1.2396x; 1.2396x over previous
//
#include <hip/hip_runtime.h>
#include <hip/hip_bf16.h>

// Problem: B=2, S=2048, H=1024, HEADS=16, HEAD_DIM=64. Wire dtype fp32; output fp32.
// R4: attn redesigned: S^T MFMA layout (cheap kv reductions), V^T precomputed in
// qkv epilogue, packed b64 P-writes, 1-wave blocks, zero barriers in attn.
#define SEQ     2048
#define BATCH   2
#define HID     1024
#define NHEADS  16
#define HD      64
#define MTOT    4096            // BATCH*SEQ
#define LNEPS   1e-6f
#define L2E     1.4426950408889634f

typedef __bf16 bf16_t;
typedef bf16_t bf16x8 __attribute__((ext_vector_type(8)));   // 4 VGPRs = one MFMA A/B frag
typedef bf16_t bf16x4 __attribute__((ext_vector_type(4)));   // b64 packed store
typedef float  floatx4 __attribute__((ext_vector_type(4)));  // one MFMA C/D frag

__device__ __forceinline__ floatx4 mfma16(bf16x8 a, bf16x8 b, floatx4 c) {
    return __builtin_amdgcn_mfma_f32_16x16x32_bf16(a, b, c, 0, 0, 0);
}
__device__ __forceinline__ bf16x8 ldg8(const bf16_t* p) { return *(const bf16x8*)p; }

// ---------------------------------------------------------------------------
// Kernel 0: fp32 -> bf16 conversion for X, Wq, Wk, Wv, Wo.
// ---------------------------------------------------------------------------
__global__ __launch_bounds__(256) void cvt_kernel(
    const float* sX, const float* sWq, const float* sWk, const float* sWv, const float* sWo,
    bf16_t* dX, bf16_t* dWq, bf16_t* dWk, bf16_t* dWv, bf16_t* dWo)
{
    const int z = blockIdx.z;
    const float* src; bf16_t* dst; int n;
    switch (z) {
        case 0:  src = sX;  dst = dX;  n = MTOT * HID; break;
        case 1:  src = sWq; dst = dWq; n = HID * HID;  break;
        case 2:  src = sWk; dst = dWk; n = HID * HID;  break;
        case 3:  src = sWv; dst = dWv; n = HID * HID;  break;
        default: src = sWo; dst = dWo; n = HID * HID;  break;
    }
    const int n4 = n >> 2;
    const int stride = gridDim.x * blockDim.x;
    for (int i = blockIdx.x * blockDim.x + threadIdx.x; i < n4; i += stride) {
        const float4 v = ((const float4*)src)[i];
        bf16_t o[4] = {(bf16_t)v.x, (bf16_t)v.y, (bf16_t)v.z, (bf16_t)v.w};
        *(unsigned long long*)(dst + 4 * i) = *(unsigned long long*)o;
    }
}

// ---------------------------------------------------------------------------
// Kernel 1: QKV projection (NT GEMM). Q pre-scaled by 0.125 (exact pow2).
// Q,K stored [bh][s][d]; V stored TRANSPOSED [bh][d][s] for the PV A-operand.
// ---------------------------------------------------------------------------
__global__ __launch_bounds__(256) void qkv_kernel(
    const bf16_t* __restrict__ X,
    const bf16_t* __restrict__ Wq, const float* __restrict__ bq,
    const bf16_t* __restrict__ Wk, const float* __restrict__ bk,
    const bf16_t* __restrict__ Wv, const float* __restrict__ bv,
    bf16_t* __restrict__ Qo, bf16_t* __restrict__ Ko, bf16_t* __restrict__ Vo)
{
    const int z = blockIdx.z;
    const bf16_t* W    = (z == 0) ? Wq : (z == 1) ? Wk : Wv;
    const float*  bias = (z == 0) ? bq : (z == 1) ? bk : bv;
    bf16_t*       out  = (z == 0) ? Qo : (z == 1) ? Ko : Vo;

    const int lane = threadIdx.x & 63;
    const int wave = threadIdx.x >> 6;
    const int l16  = lane & 15;
    const int quad = lane >> 4;
    const int m_base = blockIdx.y * 128 + (wave >> 1) * 64;
    const int n_base = blockIdx.x * 128 + (wave & 1) * 64;

    floatx4 acc[4][4];
#pragma unroll
    for (int i = 0; i < 4; i++)
#pragma unroll
        for (int j = 0; j < 4; j++) acc[i][j] = (floatx4)0.0f;

    for (int k0 = 0; k0 < HID; k0 += 32) {
        const int kk = k0 + quad * 8;
        bf16x8 a[4], b[4];
#pragma unroll
        for (int i = 0; i < 4; i++) a[i] = ldg8(X + (size_t)(m_base + i * 16 + l16) * HID + kk);
#pragma unroll
        for (int j = 0; j < 4; j++) b[j] = ldg8(W + (size_t)(n_base + j * 16 + l16) * HID + kk);
#pragma unroll
        for (int i = 0; i < 4; i++)
#pragma unroll
            for (int j = 0; j < 4; j++) acc[i][j] = mfma16(a[i], b[j], acc[i][j]);
    }

    float bv_[4];
#pragma unroll
    for (int j = 0; j < 4; j++) bv_[j] = bias[n_base + j * 16 + l16];
    const float scale = (z == 0) ? 0.125f : 1.0f;   // fold softmax 1/sqrt(64) into Q

#pragma unroll
    for (int i = 0; i < 4; i++) {
#pragma unroll
        for (int j = 0; j < 4; j++) {
            const int n = n_base + j * 16 + l16;
            const int h = n >> 6, d = n & 63;
#pragma unroll
            for (int r = 0; r < 4; r++) {
                const int m = m_base + i * 16 + quad * 4 + r;   // C layout: row=quad*4+r, col=l16
                const int bb = m >> 11, s = m & (SEQ - 1);
                const bf16_t val = (bf16_t)((acc[i][j][r] + bv_[j]) * scale);
                if (z == 2)   // V^T: [bh][d][s]
                    out[(((size_t)(bb * NHEADS + h)) * HD + d) * SEQ + s] = val;
                else          // Q/K: [bh][s][d]
                    out[(((size_t)(bb * NHEADS + h)) * SEQ + s) * HD + d] = val;
            }
        }
    }
}

// ---------------------------------------------------------------------------
// Kernel 2: flash attention, 1 wave per block, 32 q rows/wave, kv tile 64.
// S^T = K.Q^T (kv on C rows -> in-lane reductions + 2 shfl); P via b64-packed
// LDS roundtrip; O^T = V^T.P^T; no __syncthreads anywhere.
// ---------------------------------------------------------------------------
__global__ __launch_bounds__(64, 2) void attn_kernel(
    const bf16_t* __restrict__ Q, const bf16_t* __restrict__ K,
    const bf16_t* __restrict__ Vt, const int* __restrict__ mask,
    bf16_t* __restrict__ ctx)
{
    const int bh = blockIdx.y;            // 0..31
    const int b  = bh >> 4;
    const int h  = bh & 15;
    const int lane = threadIdx.x;
    const int l16  = lane & 15;
    const int quad = lane >> 4;
    const int q0 = blockIdx.x * 32;

    const bf16_t* Qh = Q  + (size_t)bh * SEQ * HD;
    const bf16_t* Kh = K  + (size_t)bh * SEQ * HD;
    const bf16_t* Vh = Vt + (size_t)bh * HD * SEQ;    // [d][s]
    const int*    mk = mask + b * SEQ;

    __shared__ __align__(16) bf16_t Pw[32 * 72];      // [32 q][64 kv + 8 pad]

    // Q B-frags (Q pre-scaled by 0.125): lane l16 = q row, k = d
    bf16x8 bQ[2][2];
#pragma unroll
    for (int qt = 0; qt < 2; qt++)
#pragma unroll
        for (int kc = 0; kc < 2; kc++)
            bQ[qt][kc] = ldg8(Qh + (size_t)(q0 + qt * 16 + l16) * HD + kc * 32 + quad * 8);

    floatx4 O[4][2];                                   // O^T[d][q]: [dt][qt]
    float mi[2] = {-1.0e30f, -1.0e30f}, li[2] = {0.0f, 0.0f};
#pragma unroll
    for (int dt = 0; dt < 4; dt++)
#pragma unroll
        for (int qt = 0; qt < 2; qt++) O[dt][qt] = (floatx4)0.0f;

    for (int kt = 0; kt < SEQ; kt += 64) {
        // ---- loads (all global, L2-resident; issued up front) ----
        int4 mv[4];
#pragma unroll
        for (int kvt = 0; kvt < 4; kvt++)
            mv[kvt] = ((const int4*)(mk + kt + kvt * 16))[quad];
        bf16x8 aK[4][2], aV[4][2];
#pragma unroll
        for (int kvt = 0; kvt < 4; kvt++)
#pragma unroll
            for (int kc = 0; kc < 2; kc++)
                aK[kvt][kc] = ldg8(Kh + (size_t)(kt + kvt * 16 + l16) * HD + kc * 32 + quad * 8);
#pragma unroll
        for (int dt = 0; dt < 4; dt++)
#pragma unroll
            for (int kc = 0; kc < 2; kc++)
                aV[dt][kc] = ldg8(Vh + (size_t)(dt * 16 + l16) * SEQ + kt + kc * 32 + quad * 8);

        // ---- S^T[kv][q]: C rows = kv (quad*4+r), cols = q (l16) ----
        floatx4 sc[4][2];
#pragma unroll
        for (int kvt = 0; kvt < 4; kvt++)
#pragma unroll
            for (int qt = 0; qt < 2; qt++) {
                floatx4 s = (floatx4)0.0f;
#pragma unroll
                for (int kc = 0; kc < 2; kc++) s = mfma16(aK[kvt][kc], bQ[qt][kc], s);
                sc[kvt][qt] = s;
            }

        // ---- online softmax per q column ----
#pragma unroll
        for (int qt = 0; qt < 2; qt++) {
            floatx4 m4 = sc[0][qt];
#pragma unroll
            for (int kvt = 1; kvt < 4; kvt++) {
#pragma unroll
                for (int r = 0; r < 4; r++) m4[r] = fmaxf(m4[r], sc[kvt][qt][r]);
            }
            float mx = fmaxf(fmaxf(m4[0], m4[1]), fmaxf(m4[2], m4[3]));
            mx = fmaxf(mx, __shfl_xor(mx, 16, 64));
            mx = fmaxf(mx, __shfl_xor(mx, 32, 64));
            const float mnew = fmaxf(mi[qt], mx);
            const float alpha = exp2f((mi[qt] - mnew) * L2E);
            mi[qt] = mnew;
            const float nm = -mnew * L2E;

            floatx4 ps = (floatx4)0.0f;
#pragma unroll
            for (int kvt = 0; kvt < 4; kvt++) {
                const int* mp = (const int*)&mv[kvt];
                floatx4 p;
#pragma unroll
                for (int r = 0; r < 4; r++)
                    p[r] = exp2f(fmaf(sc[kvt][qt][r], L2E, nm)) * (float)mp[r];
                bf16x4 pk;
#pragma unroll
                for (int r = 0; r < 4; r++) pk[r] = (bf16_t)p[r];
                *(bf16x4*)&Pw[(qt * 16 + l16) * 72 + kvt * 16 + quad * 4] = pk;
                ps += p;
            }
            float su = ps[0] + ps[1] + ps[2] + ps[3];
            su += __shfl_xor(su, 16, 64);
            su += __shfl_xor(su, 32, 64);
            li[qt] = li[qt] * alpha + su;
#pragma unroll
            for (int dt = 0; dt < 4; dt++) O[dt][qt] *= alpha;
        }

        // ---- O^T += V^T . P^T (B-frag: lane l16 = q row of Pw[q][kv]) ----
        bf16x8 bP[2][2];
#pragma unroll
        for (int qt = 0; qt < 2; qt++)
#pragma unroll
            for (int kc = 0; kc < 2; kc++)
                bP[qt][kc] = *(const bf16x8*)&Pw[(qt * 16 + l16) * 72 + kc * 32 + quad * 8];
#pragma unroll
        for (int dt = 0; dt < 4; dt++)
#pragma unroll
            for (int qt = 0; qt < 2; qt++)
#pragma unroll
                for (int kc = 0; kc < 2; kc++)
                    O[dt][qt] = mfma16(aV[dt][kc], bP[qt][kc], O[dt][qt]);
    }

    // ---- epilogue: normalize, transpose via LDS (reuse Pw as [q][d]), store ----
#pragma unroll
    for (int qt = 0; qt < 2; qt++) {
        const float linv = (li[qt] > 0.0f) ? 1.0f / li[qt] : 0.0f;
#pragma unroll
        for (int dt = 0; dt < 4; dt++) {
            floatx4 o = O[dt][qt] * linv;
            bf16x4 pk;
#pragma unroll
            for (int r = 0; r < 4; r++) pk[r] = (bf16_t)o[r];
            *(bf16x4*)&Pw[(qt * 16 + l16) * 72 + dt * 16 + quad * 4] = pk;
        }
    }
    const int row = lane >> 1;                 // 0..31 (q)
    const int cb  = (lane & 1) * 32;           // d half
#pragma unroll
    for (int k = 0; k < 4; k++) {
        bf16x8 vv = *(const bf16x8*)&Pw[row * 72 + cb + 8 * k];
        *(bf16x8*)&ctx[((size_t)(b * SEQ + q0 + row)) * HID + h * 64 + cb + 8 * k] = vv;
    }
}

// ---------------------------------------------------------------------------
// Kernel 3: res = ctx @ Wo^T + bo + hidden  -> fp32
// ---------------------------------------------------------------------------
__global__ __launch_bounds__(256) void oproj_kernel(
    const bf16_t* __restrict__ C, const bf16_t* __restrict__ Wo,
    const float* __restrict__ bo, const float* __restrict__ X,
    float* __restrict__ res)
{
    const int lane = threadIdx.x & 63;
    const int wave = threadIdx.x >> 6;
    const int l16  = lane & 15;
    const int quad = lane >> 4;
    const int m_base = blockIdx.y * 128 + (wave >> 1) * 64;
    const int n_base = blockIdx.x * 128 + (wave & 1) * 64;

    floatx4 acc[4][4];
#pragma unroll
    for (int i = 0; i < 4; i++)
#pragma unroll
        for (int j = 0; j < 4; j++) acc[i][j] = (floatx4)0.0f;

    for (int k0 = 0; k0 < HID; k0 += 32) {
        const int kk = k0 + quad * 8;
        bf16x8 a[4], b[4];
#pragma unroll
        for (int i = 0; i < 4; i++) a[i] = ldg8(C + (size_t)(m_base + i * 16 + l16) * HID + kk);
#pragma unroll
        for (int j = 0; j < 4; j++) b[j] = ldg8(Wo + (size_t)(n_base + j * 16 + l16) * HID + kk);
#pragma unroll
        for (int i = 0; i < 4; i++)
#pragma unroll
            for (int j = 0; j < 4; j++) acc[i][j] = mfma16(a[i], b[j], acc[i][j]);
    }

    float bv_[4];
#pragma unroll
    for (int j = 0; j < 4; j++) bv_[j] = bo[n_base + j * 16 + l16];

#pragma unroll
    for (int i = 0; i < 4; i++) {
#pragma unroll
        for (int j = 0; j < 4; j++) {
            const int n = n_base + j * 16 + l16;
#pragma unroll
            for (int r = 0; r < 4; r++) {
                const int m = m_base + i * 16 + quad * 4 + r;
                res[(size_t)m * HID + n] = acc[i][j][r] + bv_[j] + X[(size_t)m * HID + n];
            }
        }
    }
}

// ---------------------------------------------------------------------------
// Kernel 4: LayerNorm over rows of 1024 fp32 -> fp32 out
// ---------------------------------------------------------------------------
__global__ __launch_bounds__(256) void ln_kernel(
    const float* __restrict__ res, const float* __restrict__ g,
    const float* __restrict__ be, float* __restrict__ out)
{
    __shared__ float red1[4], red2[4];
    const int row  = blockIdx.x;
    const int lane = threadIdx.x & 63;
    const int wave = threadIdx.x >> 6;
    const float4 v = ((const float4*)(res + (size_t)row * HID))[threadIdx.x];

    float s = v.x + v.y + v.z + v.w;
#pragma unroll
    for (int off = 1; off < 64; off <<= 1) s += __shfl_xor(s, off, 64);
    if (lane == 0) red1[wave] = s;
    __syncthreads();
    const float mu = (red1[0] + red1[1] + red1[2] + red1[3]) * (1.0f / HID);

    const float d0 = v.x - mu, d1 = v.y - mu, d2 = v.z - mu, d3 = v.w - mu;
    float ss = d0 * d0 + d1 * d1 + d2 * d2 + d3 * d3;
#pragma unroll
    for (int off = 1; off < 64; off <<= 1) ss += __shfl_xor(ss, off, 64);
    if (lane == 0) red2[wave] = ss;
    __syncthreads();
    const float var = (red2[0] + red2[1] + red2[2] + red2[3]) * (1.0f / HID);
    const float rstd = rsqrtf(var + LNEPS);

    const float4 gv = ((const float4*)g)[threadIdx.x];
    const float4 bv = ((const float4*)be)[threadIdx.x];
    float4 o;
    o.x = d0 * rstd * gv.x + bv.x;
    o.y = d1 * rstd * gv.y + bv.y;
    o.z = d2 * rstd * gv.z + bv.z;
    o.w = d3 * rstd * gv.w + bv.w;
    ((float4*)(out + (size_t)row * HID))[threadIdx.x] = o;
}

// ---------------------------------------------------------------------------
extern "C" void kernel_launch(void* const* d_in, const int* in_sizes, int n_in,
                              void* d_out, int out_size, void* d_ws, size_t ws_size,
                              hipStream_t stream)
{
    const float* X  = (const float*)d_in[0];
    const int* mask = (const int*)d_in[1];
    const float* Wq = (const float*)d_in[2];  const float* bq = (const float*)d_in[3];
    const float* Wk = (const float*)d_in[4];  const float* bk = (const float*)d_in[5];
    const float* Wv = (const float*)d_in[6];  const float* bv = (const float*)d_in[7];
    const float* Wo = (const float*)d_in[8];  const float* bo = (const float*)d_in[9];
    const float* g  = (const float*)d_in[10]; const float* be = (const float*)d_in[11];
    float* out = (float*)d_out;

    char* ws = (char*)d_ws;
    bf16_t* Qb  = (bf16_t*)(ws);                          // [0, 8M)
    bf16_t* Kb  = (bf16_t*)(ws + (8ull  << 20));          // [8M, 16M)
    bf16_t* Vb  = (bf16_t*)(ws + (16ull << 20));          // [16M, 24M)  V^T [bh][d][s]
    bf16_t* Cb  = (bf16_t*)(ws + (24ull << 20));          // [24M, 32M)
    float*  Rb  = (float*)(ws);                           // [0, 16M) aliases dead Q/K
    bf16_t* Xc  = (bf16_t*)(ws + (32ull << 20));          // [32M, 40M)
    bf16_t* Wqc = (bf16_t*)(ws + (40ull << 20));
    bf16_t* Wkc = (bf16_t*)(ws + (42ull << 20));
    bf16_t* Wvc = (bf16_t*)(ws + (44ull << 20));
    bf16_t* Woc = (bf16_t*)(ws + (46ull << 20));

    cvt_kernel <<<dim3(128, 1, 5), 256, 0, stream>>>(X, Wq, Wk, Wv, Wo, Xc, Wqc, Wkc, Wvc, Woc);
    qkv_kernel <<<dim3(8, 32, 3), 256, 0, stream>>>(Xc, Wqc, bq, Wkc, bk, Wvc, bv, Qb, Kb, Vb);
    attn_kernel<<<dim3(SEQ / 32, BATCH * NHEADS), 64, 0, stream>>>(Qb, Kb, Vb, mask, Cb);
    oproj_kernel<<<dim3(8, 32), 256, 0, stream>>>(Cb, Woc, bo, X, Rb);
    ln_kernel  <<<MTOT, 256, 0, stream>>>(Rb, g, be, out);
}

// Round 5
// 366.481 us; speedup vs baseline: 1.2479x; 1.0067x over previous
//
#include <hip/hip_runtime.h>
#include <hip/hip_bf16.h>

// Problem: B=2, S=2048, H=1024, HEADS=16, HEAD_DIM=64. Wire dtype fp32; output fp32.
// R5: attn softmax -> static-shift (exact: softmax shift-invariant; s~N(0,1) so
// exp2(1.443 s - 26) can't over/underflow), denominator deferred to epilogue.
// Loop has ZERO cross-lane ops and no O-rescale. XCD-aware block swizzle.
#define SEQ     2048
#define BATCH   2
#define HID     1024
#define NHEADS  16
#define HD      64
#define MTOT    4096            // BATCH*SEQ
#define LNEPS   1e-6f
#define L2E     1.4426950408889634f
#define SHIFT2  26.0f           // base-2 static softmax shift

typedef __bf16 bf16_t;
typedef bf16_t bf16x8 __attribute__((ext_vector_type(8)));   // 4 VGPRs = one MFMA A/B frag
typedef bf16_t bf16x4 __attribute__((ext_vector_type(4)));   // b64 packed store
typedef float  floatx4 __attribute__((ext_vector_type(4)));  // one MFMA C/D frag

__device__ __forceinline__ floatx4 mfma16(bf16x8 a, bf16x8 b, floatx4 c) {
    return __builtin_amdgcn_mfma_f32_16x16x32_bf16(a, b, c, 0, 0, 0);
}
__device__ __forceinline__ bf16x8 ldg8(const bf16_t* p) { return *(const bf16x8*)p; }

// ---------------------------------------------------------------------------
// Kernel 0: fp32 -> bf16 conversion for X, Wq, Wk, Wv, Wo.
// ---------------------------------------------------------------------------
__global__ __launch_bounds__(256) void cvt_kernel(
    const float* sX, const float* sWq, const float* sWk, const float* sWv, const float* sWo,
    bf16_t* dX, bf16_t* dWq, bf16_t* dWk, bf16_t* dWv, bf16_t* dWo)
{
    const int z = blockIdx.z;
    const float* src; bf16_t* dst; int n;
    switch (z) {
        case 0:  src = sX;  dst = dX;  n = MTOT * HID; break;
        case 1:  src = sWq; dst = dWq; n = HID * HID;  break;
        case 2:  src = sWk; dst = dWk; n = HID * HID;  break;
        case 3:  src = sWv; dst = dWv; n = HID * HID;  break;
        default: src = sWo; dst = dWo; n = HID * HID;  break;
    }
    const int n4 = n >> 2;
    const int stride = gridDim.x * blockDim.x;
    for (int i = blockIdx.x * blockDim.x + threadIdx.x; i < n4; i += stride) {
        const float4 v = ((const float4*)src)[i];
        bf16_t o[4] = {(bf16_t)v.x, (bf16_t)v.y, (bf16_t)v.z, (bf16_t)v.w};
        *(unsigned long long*)(dst + 4 * i) = *(unsigned long long*)o;
    }
}

// ---------------------------------------------------------------------------
// Kernel 1: QKV projection (NT GEMM). Q pre-scaled by 0.125 (exact pow2).
// Q,K stored [bh][s][d]; V stored TRANSPOSED [bh][d][s] for the PV A-operand.
// ---------------------------------------------------------------------------
__global__ __launch_bounds__(256) void qkv_kernel(
    const bf16_t* __restrict__ X,
    const bf16_t* __restrict__ Wq, const float* __restrict__ bq,
    const bf16_t* __restrict__ Wk, const float* __restrict__ bk,
    const bf16_t* __restrict__ Wv, const float* __restrict__ bv,
    bf16_t* __restrict__ Qo, bf16_t* __restrict__ Ko, bf16_t* __restrict__ Vo)
{
    const int z = blockIdx.z;
    const bf16_t* W    = (z == 0) ? Wq : (z == 1) ? Wk : Wv;
    const float*  bias = (z == 0) ? bq : (z == 1) ? bk : bv;
    bf16_t*       out  = (z == 0) ? Qo : (z == 1) ? Ko : Vo;

    const int lane = threadIdx.x & 63;
    const int wave = threadIdx.x >> 6;
    const int l16  = lane & 15;
    const int quad = lane >> 4;
    const int m_base = blockIdx.y * 128 + (wave >> 1) * 64;
    const int n_base = blockIdx.x * 128 + (wave & 1) * 64;

    floatx4 acc[4][4];
#pragma unroll
    for (int i = 0; i < 4; i++)
#pragma unroll
        for (int j = 0; j < 4; j++) acc[i][j] = (floatx4)0.0f;

    for (int k0 = 0; k0 < HID; k0 += 32) {
        const int kk = k0 + quad * 8;
        bf16x8 a[4], b[4];
#pragma unroll
        for (int i = 0; i < 4; i++) a[i] = ldg8(X + (size_t)(m_base + i * 16 + l16) * HID + kk);
#pragma unroll
        for (int j = 0; j < 4; j++) b[j] = ldg8(W + (size_t)(n_base + j * 16 + l16) * HID + kk);
#pragma unroll
        for (int i = 0; i < 4; i++)
#pragma unroll
            for (int j = 0; j < 4; j++) acc[i][j] = mfma16(a[i], b[j], acc[i][j]);
    }

    float bv_[4];
#pragma unroll
    for (int j = 0; j < 4; j++) bv_[j] = bias[n_base + j * 16 + l16];
    const float scale = (z == 0) ? 0.125f : 1.0f;   // fold softmax 1/sqrt(64) into Q

#pragma unroll
    for (int i = 0; i < 4; i++) {
#pragma unroll
        for (int j = 0; j < 4; j++) {
            const int n = n_base + j * 16 + l16;
            const int h = n >> 6, d = n & 63;
#pragma unroll
            for (int r = 0; r < 4; r++) {
                const int m = m_base + i * 16 + quad * 4 + r;   // C layout: row=quad*4+r, col=l16
                const int bb = m >> 11, s = m & (SEQ - 1);
                const bf16_t val = (bf16_t)((acc[i][j][r] + bv_[j]) * scale);
                if (z == 2)   // V^T: [bh][d][s]
                    out[(((size_t)(bb * NHEADS + h)) * HD + d) * SEQ + s] = val;
                else          // Q/K: [bh][s][d]
                    out[(((size_t)(bb * NHEADS + h)) * SEQ + s) * HD + d] = val;
            }
        }
    }
}

// ---------------------------------------------------------------------------
// Kernel 2: flash attention, 1 wave/block, 32 q rows, kv tile 64, no barriers.
// Static-shift softmax: p = exp2(s*log2e - 26); O and l accumulate unscaled;
// single normalization in the epilogue. Zero cross-lane ops in the loop.
// 1-D grid with XCD-aware swizzle: each XCD owns 4 heads (K/V fits its L2).
// ---------------------------------------------------------------------------
__global__ __launch_bounds__(64, 2) void attn_kernel(
    const bf16_t* __restrict__ Q, const bf16_t* __restrict__ K,
    const bf16_t* __restrict__ Vt, const int* __restrict__ mask,
    bf16_t* __restrict__ ctx)
{
    const int B = blockIdx.x;                 // 0..2047
    const int bh = 4 * (B & 7) + ((B >> 3) & 3);   // XCD k -> heads 4k..4k+3
    const int q0 = (B >> 5) * 32;
    const int b  = bh >> 4;
    const int h  = bh & 15;
    const int lane = threadIdx.x;
    const int l16  = lane & 15;
    const int quad = lane >> 4;

    const bf16_t* Qh = Q  + (size_t)bh * SEQ * HD;
    const bf16_t* Kh = K  + (size_t)bh * SEQ * HD;
    const bf16_t* Vh = Vt + (size_t)bh * HD * SEQ;    // [d][s]
    const int*    mk = mask + b * SEQ;

    __shared__ __align__(16) bf16_t Pw[32 * 72];      // [32 q][64 kv + 8 pad]

    // Q B-frags (pre-scaled by 0.125): lane l16 = q row, k = d
    bf16x8 bQ[2][2];
#pragma unroll
    for (int qt = 0; qt < 2; qt++)
#pragma unroll
        for (int kc = 0; kc < 2; kc++)
            bQ[qt][kc] = ldg8(Qh + (size_t)(q0 + qt * 16 + l16) * HD + kc * 32 + quad * 8);

    floatx4 O[4][2];                                   // O^T[d][q]: [dt][qt]
    floatx4 psum[2] = {(floatx4)0.0f, (floatx4)0.0f};  // per-lane partial denominators
#pragma unroll
    for (int dt = 0; dt < 4; dt++)
#pragma unroll
        for (int qt = 0; qt < 2; qt++) O[dt][qt] = (floatx4)0.0f;

    for (int kt = 0; kt < SEQ; kt += 64) {
        // ---- loads (global, L2-resident; issued up front) ----
        int4 mv[4];
#pragma unroll
        for (int kvt = 0; kvt < 4; kvt++)
            mv[kvt] = ((const int4*)(mk + kt + kvt * 16))[quad];
        bf16x8 aK[4][2], aV[4][2];
#pragma unroll
        for (int kvt = 0; kvt < 4; kvt++)
#pragma unroll
            for (int kc = 0; kc < 2; kc++)
                aK[kvt][kc] = ldg8(Kh + (size_t)(kt + kvt * 16 + l16) * HD + kc * 32 + quad * 8);
#pragma unroll
        for (int dt = 0; dt < 4; dt++)
#pragma unroll
            for (int kc = 0; kc < 2; kc++)
                aV[dt][kc] = ldg8(Vh + (size_t)(dt * 16 + l16) * SEQ + kt + kc * 32 + quad * 8);

        // ---- S^T[kv][q]: C rows = kv (quad*4+r), cols = q (l16) ----
#pragma unroll
        for (int qt = 0; qt < 2; qt++) {
#pragma unroll
            for (int kvt = 0; kvt < 4; kvt++) {
                floatx4 s = (floatx4)0.0f;
#pragma unroll
                for (int kc = 0; kc < 2; kc++) s = mfma16(aK[kvt][kc], bQ[qt][kc], s);
                // p = exp2(s*L2E - 26) * mask  (static shift; exact softmax)
                const int* mp = (const int*)&mv[kvt];
                floatx4 p;
#pragma unroll
                for (int r = 0; r < 4; r++)
                    p[r] = exp2f(fmaf(s[r], L2E, -SHIFT2)) * (float)mp[r];
                bf16x4 pk;
#pragma unroll
                for (int r = 0; r < 4; r++) pk[r] = (bf16_t)p[r];
                *(bf16x4*)&Pw[(qt * 16 + l16) * 72 + kvt * 16 + quad * 4] = pk;
                psum[qt] += p;
            }
        }

        // ---- O^T += V^T . P^T (B-frag: lane l16 = q row of Pw[q][kv]) ----
        bf16x8 bP[2][2];
#pragma unroll
        for (int qt = 0; qt < 2; qt++)
#pragma unroll
            for (int kc = 0; kc < 2; kc++)
                bP[qt][kc] = *(const bf16x8*)&Pw[(qt * 16 + l16) * 72 + kc * 32 + quad * 8];
#pragma unroll
        for (int dt = 0; dt < 4; dt++)
#pragma unroll
            for (int qt = 0; qt < 2; qt++)
#pragma unroll
                for (int kc = 0; kc < 2; kc++)
                    O[dt][qt] = mfma16(aV[dt][kc], bP[qt][kc], O[dt][qt]);
    }

    // ---- epilogue: reduce denominators (only cross-lane ops in the kernel) ----
    float li[2];
#pragma unroll
    for (int qt = 0; qt < 2; qt++) {
        float su = psum[qt][0] + psum[qt][1] + psum[qt][2] + psum[qt][3];
        su += __shfl_xor(su, 16, 64);
        su += __shfl_xor(su, 32, 64);
        li[qt] = su;
    }
    // normalize, transpose via LDS (reuse Pw as [q][d]), store
#pragma unroll
    for (int qt = 0; qt < 2; qt++) {
        const float linv = (li[qt] > 0.0f) ? 1.0f / li[qt] : 0.0f;
#pragma unroll
        for (int dt = 0; dt < 4; dt++) {
            floatx4 o = O[dt][qt] * linv;
            bf16x4 pk;
#pragma unroll
            for (int r = 0; r < 4; r++) pk[r] = (bf16_t)o[r];
            *(bf16x4*)&Pw[(qt * 16 + l16) * 72 + dt * 16 + quad * 4] = pk;
        }
    }
    const int row = lane >> 1;                 // 0..31 (q)
    const int cb  = (lane & 1) * 32;           // d half
#pragma unroll
    for (int k = 0; k < 4; k++) {
        bf16x8 vv = *(const bf16x8*)&Pw[row * 72 + cb + 8 * k];
        *(bf16x8*)&ctx[((size_t)(b * SEQ + q0 + row)) * HID + h * 64 + cb + 8 * k] = vv;
    }
}

// ---------------------------------------------------------------------------
// Kernel 3: res = ctx @ Wo^T + bo + hidden  -> fp32
// ---------------------------------------------------------------------------
__global__ __launch_bounds__(256) void oproj_kernel(
    const bf16_t* __restrict__ C, const bf16_t* __restrict__ Wo,
    const float* __restrict__ bo, const float* __restrict__ X,
    float* __restrict__ res)
{
    const int lane = threadIdx.x & 63;
    const int wave = threadIdx.x >> 6;
    const int l16  = lane & 15;
    const int quad = lane >> 4;
    const int m_base = blockIdx.y * 128 + (wave >> 1) * 64;
    const int n_base = blockIdx.x * 128 + (wave & 1) * 64;

    floatx4 acc[4][4];
#pragma unroll
    for (int i = 0; i < 4; i++)
#pragma unroll
        for (int j = 0; j < 4; j++) acc[i][j] = (floatx4)0.0f;

    for (int k0 = 0; k0 < HID; k0 += 32) {
        const int kk = k0 + quad * 8;
        bf16x8 a[4], b[4];
#pragma unroll
        for (int i = 0; i < 4; i++) a[i] = ldg8(C + (size_t)(m_base + i * 16 + l16) * HID + kk);
#pragma unroll
        for (int j = 0; j < 4; j++) b[j] = ldg8(Wo + (size_t)(n_base + j * 16 + l16) * HID + kk);
#pragma unroll
        for (int i = 0; i < 4; i++)
#pragma unroll
            for (int j = 0; j < 4; j++) acc[i][j] = mfma16(a[i], b[j], acc[i][j]);
    }

    float bv_[4];
#pragma unroll
    for (int j = 0; j < 4; j++) bv_[j] = bo[n_base + j * 16 + l16];

#pragma unroll
    for (int i = 0; i < 4; i++) {
#pragma unroll
        for (int j = 0; j < 4; j++) {
            const int n = n_base + j * 16 + l16;
#pragma unroll
            for (int r = 0; r < 4; r++) {
                const int m = m_base + i * 16 + quad * 4 + r;
                res[(size_t)m * HID + n] = acc[i][j][r] + bv_[j] + X[(size_t)m * HID + n];
            }
        }
    }
}

// ---------------------------------------------------------------------------
// Kernel 4: LayerNorm over rows of 1024 fp32 -> fp32 out
// ---------------------------------------------------------------------------
__global__ __launch_bounds__(256) void ln_kernel(
    const float* __restrict__ res, const float* __restrict__ g,
    const float* __restrict__ be, float* __restrict__ out)
{
    __shared__ float red1[4], red2[4];
    const int row  = blockIdx.x;
    const int lane = threadIdx.x & 63;
    const int wave = threadIdx.x >> 6;
    const float4 v = ((const float4*)(res + (size_t)row * HID))[threadIdx.x];

    float s = v.x + v.y + v.z + v.w;
#pragma unroll
    for (int off = 1; off < 64; off <<= 1) s += __shfl_xor(s, off, 64);
    if (lane == 0) red1[wave] = s;
    __syncthreads();
    const float mu = (red1[0] + red1[1] + red1[2] + red1[3]) * (1.0f / HID);

    const float d0 = v.x - mu, d1 = v.y - mu, d2 = v.z - mu, d3 = v.w - mu;
    float ss = d0 * d0 + d1 * d1 + d2 * d2 + d3 * d3;
#pragma unroll
    for (int off = 1; off < 64; off <<= 1) ss += __shfl_xor(ss, off, 64);
    if (lane == 0) red2[wave] = ss;
    __syncthreads();
    const float var = (red2[0] + red2[1] + red2[2] + red2[3]) * (1.0f / HID);
    const float rstd = rsqrtf(var + LNEPS);

    const float4 gv = ((const float4*)g)[threadIdx.x];
    const float4 bv = ((const float4*)be)[threadIdx.x];
    float4 o;
    o.x = d0 * rstd * gv.x + bv.x;
    o.y = d1 * rstd * gv.y + bv.y;
    o.z = d2 * rstd * gv.z + bv.z;
    o.w = d3 * rstd * gv.w + bv.w;
    ((float4*)(out + (size_t)row * HID))[threadIdx.x] = o;
}

// ---------------------------------------------------------------------------
extern "C" void kernel_launch(void* const* d_in, const int* in_sizes, int n_in,
                              void* d_out, int out_size, void* d_ws, size_t ws_size,
                              hipStream_t stream)
{
    const float* X  = (const float*)d_in[0];
    const int* mask = (const int*)d_in[1];
    const float* Wq = (const float*)d_in[2];  const float* bq = (const float*)d_in[3];
    const float* Wk = (const float*)d_in[4];  const float* bk = (const float*)d_in[5];
    const float* Wv = (const float*)d_in[6];  const float* bv = (const float*)d_in[7];
    const float* Wo = (const float*)d_in[8];  const float* bo = (const float*)d_in[9];
    const float* g  = (const float*)d_in[10]; const float* be = (const float*)d_in[11];
    float* out = (float*)d_out;

    char* ws = (char*)d_ws;
    bf16_t* Qb  = (bf16_t*)(ws);                          // [0, 8M)
    bf16_t* Kb  = (bf16_t*)(ws + (8ull  << 20));          // [8M, 16M)
    bf16_t* Vb  = (bf16_t*)(ws + (16ull << 20));          // [16M, 24M)  V^T [bh][d][s]
    bf16_t* Cb  = (bf16_t*)(ws + (24ull << 20));          // [24M, 32M)
    float*  Rb  = (float*)(ws);                           // [0, 16M) aliases dead Q/K
    bf16_t* Xc  = (bf16_t*)(ws + (32ull << 20));          // [32M, 40M)
    bf16_t* Wqc = (bf16_t*)(ws + (40ull << 20));
    bf16_t* Wkc = (bf16_t*)(ws + (42ull << 20));
    bf16_t* Wvc = (bf16_t*)(ws + (44ull << 20));
    bf16_t* Woc = (bf16_t*)(ws + (46ull << 20));

    cvt_kernel <<<dim3(128, 1, 5), 256, 0, stream>>>(X, Wq, Wk, Wv, Wo, Xc, Wqc, Wkc, Wvc, Woc);
    qkv_kernel <<<dim3(8, 32, 3), 256, 0, stream>>>(Xc, Wqc, bq, Wkc, bk, Wvc, bv, Qb, Kb, Vb);
    attn_kernel<<<dim3((SEQ / 32) * BATCH * NHEADS), 64, 0, stream>>>(Qb, Kb, Vb, mask, Cb);
    oproj_kernel<<<dim3(8, 32), 256, 0, stream>>>(Cb, Woc, bo, X, Rb);
    ln_kernel  <<<MTOT, 256, 0, stream>>>(Rb, g, be, out);
}

// Round 6
// 316.018 us; speedup vs baseline: 1.4471x; 1.1597x over previous
//
#include <hip/hip_runtime.h>
#include <hip/hip_bf16.h>

// Problem: B=2, S=2048, H=1024, HEADS=16, HEAD_DIM=64. Wire dtype fp32; output fp32.
// R6: attn restructured for occupancy+locality: 4-wave blocks, 16 q/wave,
// K/V^T tiles staged in LDS (dense loads, 4-way shared), 4096 waves = 4/SIMD.
// Static-shift softmax kept (exact; zero cross-lane ops in loop).
#define SEQ     2048
#define BATCH   2
#define HID     1024
#define NHEADS  16
#define HD      64
#define MTOT    4096            // BATCH*SEQ
#define LNEPS   1e-6f
#define L2E     1.4426950408889634f
#define SHIFT2  26.0f           // base-2 static softmax shift

typedef __bf16 bf16_t;
typedef bf16_t bf16x8 __attribute__((ext_vector_type(8)));   // 4 VGPRs = one MFMA A/B frag
typedef bf16_t bf16x4 __attribute__((ext_vector_type(4)));   // b64 packed store
typedef float  floatx4 __attribute__((ext_vector_type(4)));  // one MFMA C/D frag

__device__ __forceinline__ floatx4 mfma16(bf16x8 a, bf16x8 b, floatx4 c) {
    return __builtin_amdgcn_mfma_f32_16x16x32_bf16(a, b, c, 0, 0, 0);
}
__device__ __forceinline__ bf16x8 ldg8(const bf16_t* p) { return *(const bf16x8*)p; }

// ---------------------------------------------------------------------------
// Kernel 0: fp32 -> bf16 conversion for X, Wq, Wk, Wv, Wo.
// ---------------------------------------------------------------------------
__global__ __launch_bounds__(256) void cvt_kernel(
    const float* sX, const float* sWq, const float* sWk, const float* sWv, const float* sWo,
    bf16_t* dX, bf16_t* dWq, bf16_t* dWk, bf16_t* dWv, bf16_t* dWo)
{
    const int z = blockIdx.z;
    const float* src; bf16_t* dst; int n;
    switch (z) {
        case 0:  src = sX;  dst = dX;  n = MTOT * HID; break;
        case 1:  src = sWq; dst = dWq; n = HID * HID;  break;
        case 2:  src = sWk; dst = dWk; n = HID * HID;  break;
        case 3:  src = sWv; dst = dWv; n = HID * HID;  break;
        default: src = sWo; dst = dWo; n = HID * HID;  break;
    }
    const int n4 = n >> 2;
    const int stride = gridDim.x * blockDim.x;
    for (int i = blockIdx.x * blockDim.x + threadIdx.x; i < n4; i += stride) {
        const float4 v = ((const float4*)src)[i];
        bf16_t o[4] = {(bf16_t)v.x, (bf16_t)v.y, (bf16_t)v.z, (bf16_t)v.w};
        *(unsigned long long*)(dst + 4 * i) = *(unsigned long long*)o;
    }
}

// ---------------------------------------------------------------------------
// Kernel 1: QKV projection (NT GEMM). Q pre-scaled by 0.125 (exact pow2).
// Q,K stored [bh][s][d]; V stored TRANSPOSED [bh][d][s] for the PV A-operand.
// ---------------------------------------------------------------------------
__global__ __launch_bounds__(256) void qkv_kernel(
    const bf16_t* __restrict__ X,
    const bf16_t* __restrict__ Wq, const float* __restrict__ bq,
    const bf16_t* __restrict__ Wk, const float* __restrict__ bk,
    const bf16_t* __restrict__ Wv, const float* __restrict__ bv,
    bf16_t* __restrict__ Qo, bf16_t* __restrict__ Ko, bf16_t* __restrict__ Vo)
{
    const int z = blockIdx.z;
    const bf16_t* W    = (z == 0) ? Wq : (z == 1) ? Wk : Wv;
    const float*  bias = (z == 0) ? bq : (z == 1) ? bk : bv;
    bf16_t*       out  = (z == 0) ? Qo : (z == 1) ? Ko : Vo;

    const int lane = threadIdx.x & 63;
    const int wave = threadIdx.x >> 6;
    const int l16  = lane & 15;
    const int quad = lane >> 4;
    const int m_base = blockIdx.y * 128 + (wave >> 1) * 64;
    const int n_base = blockIdx.x * 128 + (wave & 1) * 64;

    floatx4 acc[4][4];
#pragma unroll
    for (int i = 0; i < 4; i++)
#pragma unroll
        for (int j = 0; j < 4; j++) acc[i][j] = (floatx4)0.0f;

    for (int k0 = 0; k0 < HID; k0 += 32) {
        const int kk = k0 + quad * 8;
        bf16x8 a[4], b[4];
#pragma unroll
        for (int i = 0; i < 4; i++) a[i] = ldg8(X + (size_t)(m_base + i * 16 + l16) * HID + kk);
#pragma unroll
        for (int j = 0; j < 4; j++) b[j] = ldg8(W + (size_t)(n_base + j * 16 + l16) * HID + kk);
#pragma unroll
        for (int i = 0; i < 4; i++)
#pragma unroll
            for (int j = 0; j < 4; j++) acc[i][j] = mfma16(a[i], b[j], acc[i][j]);
    }

    float bv_[4];
#pragma unroll
    for (int j = 0; j < 4; j++) bv_[j] = bias[n_base + j * 16 + l16];
    const float scale = (z == 0) ? 0.125f : 1.0f;   // fold softmax 1/sqrt(64) into Q

#pragma unroll
    for (int i = 0; i < 4; i++) {
#pragma unroll
        for (int j = 0; j < 4; j++) {
            const int n = n_base + j * 16 + l16;
            const int h = n >> 6, d = n & 63;
#pragma unroll
            for (int r = 0; r < 4; r++) {
                const int m = m_base + i * 16 + quad * 4 + r;   // C layout: row=quad*4+r, col=l16
                const int bb = m >> 11, s = m & (SEQ - 1);
                const bf16_t val = (bf16_t)((acc[i][j][r] + bv_[j]) * scale);
                if (z == 2)   // V^T: [bh][d][s]
                    out[(((size_t)(bb * NHEADS + h)) * HD + d) * SEQ + s] = val;
                else          // Q/K: [bh][s][d]
                    out[(((size_t)(bb * NHEADS + h)) * SEQ + s) * HD + d] = val;
            }
        }
    }
}

// ---------------------------------------------------------------------------
// Kernel 2: flash attention. Block = 4 waves (256 thr); wave owns 16 q rows
// (block = 64 q). kv tile 64: K[64][64] and V^T[64][64] staged in LDS (stride
// 72) by all 256 threads with DENSE global loads, consumed by all 4 waves.
// Static-shift softmax (p = exp2(s*log2e - 26)); denominators deferred to
// epilogue; zero cross-lane ops in the loop. Grid 1024 blocks = 4/SIMD.
// XCD swizzle: XCD k owns heads 4k..4k+3 (2 MB K/V per XCD L2).
// ---------------------------------------------------------------------------
__global__ __launch_bounds__(256, 4) void attn_kernel(
    const bf16_t* __restrict__ Q, const bf16_t* __restrict__ K,
    const bf16_t* __restrict__ Vt, const int* __restrict__ mask,
    bf16_t* __restrict__ ctx)
{
    const int B   = blockIdx.x;            // 0..1023
    const int xcd = B & 7;
    const int idx = B >> 3;                // 0..127
    const int bh  = xcd * 4 + (idx & 3);
    const int q0  = (idx >> 2) * 64;       // block q base (32 q-blocks)
    const int b   = bh >> 4;
    const int h   = bh & 15;
    const int tid  = threadIdx.x;
    const int wave = tid >> 6;
    const int lane = tid & 63;
    const int l16  = lane & 15;
    const int quad = lane >> 4;

    const bf16_t* Qh = Q  + (size_t)bh * SEQ * HD;
    const bf16_t* Kh = K  + (size_t)bh * SEQ * HD;
    const bf16_t* Vh = Vt + (size_t)bh * HD * SEQ;    // [d][s]
    const int*    mk = mask + b * SEQ;

    __shared__ __align__(16) bf16_t Ks[64 * 72];      // K tile  [kv][d]
    __shared__ __align__(16) bf16_t Vs[64 * 72];      // V^T tile [d][kv]
    __shared__ __align__(16) bf16_t Pl[4][16 * 72];   // per-wave P [q][kv]

    bf16_t* Pw = Pl[wave];
    const int qw = q0 + wave * 16;

    // Q B-frags (pre-scaled by 0.125): lane l16 = q row, k = d
    bf16x8 bQ[2];
#pragma unroll
    for (int kc = 0; kc < 2; kc++)
        bQ[kc] = ldg8(Qh + (size_t)(qw + l16) * HD + kc * 32 + quad * 8);

    floatx4 O[4];                          // O^T[d][q=l16], dt = d/16
    floatx4 psum = (floatx4)0.0f;
#pragma unroll
    for (int dt = 0; dt < 4; dt++) O[dt] = (floatx4)0.0f;

    // staging decomposition: 512 16B-chunks per tile pair half; thread -> 2 rows
    const int r0 = tid >> 3;               // 0..31
    const int c0 = (tid & 7) * 8;          // elems 0..56

    for (int kt = 0; kt < SEQ; kt += 64) {
        // dense global loads for this tile (issued before the WAR barrier)
        bf16x8 k0v = ldg8(Kh + (size_t)(kt + r0)      * HD + c0);
        bf16x8 k1v = ldg8(Kh + (size_t)(kt + 32 + r0) * HD + c0);
        bf16x8 v0v = ldg8(Vh + (size_t)(r0)      * SEQ + kt + c0);
        bf16x8 v1v = ldg8(Vh + (size_t)(32 + r0) * SEQ + kt + c0);
        int4 mv[4];
#pragma unroll
        for (int kvt = 0; kvt < 4; kvt++)
            mv[kvt] = ((const int4*)(mk + kt + kvt * 16))[quad];

        __syncthreads();                   // WAR: prev iter's reads done
        *(bf16x8*)&Ks[r0 * 72 + c0]        = k0v;
        *(bf16x8*)&Ks[(32 + r0) * 72 + c0] = k1v;
        *(bf16x8*)&Vs[r0 * 72 + c0]        = v0v;
        *(bf16x8*)&Vs[(32 + r0) * 72 + c0] = v1v;
        __syncthreads();                   // RAW: tiles visible

        // ---- S^T[kv][q] + exp + pack P ----
#pragma unroll
        for (int kvt = 0; kvt < 4; kvt++) {
            floatx4 s = (floatx4)0.0f;
#pragma unroll
            for (int kc = 0; kc < 2; kc++) {
                bf16x8 aK = *(const bf16x8*)&Ks[(kvt * 16 + l16) * 72 + kc * 32 + quad * 8];
                s = mfma16(aK, bQ[kc], s);
            }
            const int* mp = (const int*)&mv[kvt];
            floatx4 p;
#pragma unroll
            for (int r = 0; r < 4; r++)
                p[r] = exp2f(fmaf(s[r], L2E, -SHIFT2)) * (float)mp[r];
            bf16x4 pk;
#pragma unroll
            for (int r = 0; r < 4; r++) pk[r] = (bf16_t)p[r];
            *(bf16x4*)&Pw[l16 * 72 + kvt * 16 + quad * 4] = pk;
            psum += p;
        }

        // ---- O^T += V^T . P^T ----
        bf16x8 bP[2];
#pragma unroll
        for (int kc = 0; kc < 2; kc++)
            bP[kc] = *(const bf16x8*)&Pw[l16 * 72 + kc * 32 + quad * 8];
#pragma unroll
        for (int dt = 0; dt < 4; dt++)
#pragma unroll
            for (int kc = 0; kc < 2; kc++) {
                bf16x8 aV = *(const bf16x8*)&Vs[(dt * 16 + l16) * 72 + kc * 32 + quad * 8];
                O[dt] = mfma16(aV, bP[kc], O[dt]);
            }
    }

    // ---- epilogue: denominator (only cross-lane ops in the kernel) ----
    float su = psum[0] + psum[1] + psum[2] + psum[3];
    su += __shfl_xor(su, 16, 64);
    su += __shfl_xor(su, 32, 64);
    const float linv = (su > 0.0f) ? 1.0f / su : 0.0f;

    // normalize + transpose via per-wave Pw ([q][d]) + coalesced store
#pragma unroll
    for (int dt = 0; dt < 4; dt++) {
        floatx4 o = O[dt] * linv;
        bf16x4 pk;
#pragma unroll
        for (int r = 0; r < 4; r++) pk[r] = (bf16_t)o[r];
        *(bf16x4*)&Pw[l16 * 72 + dt * 16 + quad * 4] = pk;
    }
#pragma unroll
    for (int ch = 0; ch < 2; ch++) {
        const int cc  = ch * 64 + lane;        // 0..127
        const int row = cc >> 3;               // q row 0..15
        const int col = (cc & 7) * 8;          // d col
        bf16x8 vv = *(const bf16x8*)&Pw[row * 72 + col];
        *(bf16x8*)&ctx[((size_t)(b * SEQ + qw + row)) * HID + h * 64 + col] = vv;
    }
}

// ---------------------------------------------------------------------------
// Kernel 3: res = ctx @ Wo^T + bo + hidden  -> fp32
// ---------------------------------------------------------------------------
__global__ __launch_bounds__(256) void oproj_kernel(
    const bf16_t* __restrict__ C, const bf16_t* __restrict__ Wo,
    const float* __restrict__ bo, const float* __restrict__ X,
    float* __restrict__ res)
{
    const int lane = threadIdx.x & 63;
    const int wave = threadIdx.x >> 6;
    const int l16  = lane & 15;
    const int quad = lane >> 4;
    const int m_base = blockIdx.y * 128 + (wave >> 1) * 64;
    const int n_base = blockIdx.x * 128 + (wave & 1) * 64;

    floatx4 acc[4][4];
#pragma unroll
    for (int i = 0; i < 4; i++)
#pragma unroll
        for (int j = 0; j < 4; j++) acc[i][j] = (floatx4)0.0f;

    for (int k0 = 0; k0 < HID; k0 += 32) {
        const int kk = k0 + quad * 8;
        bf16x8 a[4], b[4];
#pragma unroll
        for (int i = 0; i < 4; i++) a[i] = ldg8(C + (size_t)(m_base + i * 16 + l16) * HID + kk);
#pragma unroll
        for (int j = 0; j < 4; j++) b[j] = ldg8(Wo + (size_t)(n_base + j * 16 + l16) * HID + kk);
#pragma unroll
        for (int i = 0; i < 4; i++)
#pragma unroll
            for (int j = 0; j < 4; j++) acc[i][j] = mfma16(a[i], b[j], acc[i][j]);
    }

    float bv_[4];
#pragma unroll
    for (int j = 0; j < 4; j++) bv_[j] = bo[n_base + j * 16 + l16];

#pragma unroll
    for (int i = 0; i < 4; i++) {
#pragma unroll
        for (int j = 0; j < 4; j++) {
            const int n = n_base + j * 16 + l16;
#pragma unroll
            for (int r = 0; r < 4; r++) {
                const int m = m_base + i * 16 + quad * 4 + r;
                res[(size_t)m * HID + n] = acc[i][j][r] + bv_[j] + X[(size_t)m * HID + n];
            }
        }
    }
}

// ---------------------------------------------------------------------------
// Kernel 4: LayerNorm over rows of 1024 fp32 -> fp32 out
// ---------------------------------------------------------------------------
__global__ __launch_bounds__(256) void ln_kernel(
    const float* __restrict__ res, const float* __restrict__ g,
    const float* __restrict__ be, float* __restrict__ out)
{
    __shared__ float red1[4], red2[4];
    const int row  = blockIdx.x;
    const int lane = threadIdx.x & 63;
    const int wave = threadIdx.x >> 6;
    const float4 v = ((const float4*)(res + (size_t)row * HID))[threadIdx.x];

    float s = v.x + v.y + v.z + v.w;
#pragma unroll
    for (int off = 1; off < 64; off <<= 1) s += __shfl_xor(s, off, 64);
    if (lane == 0) red1[wave] = s;
    __syncthreads();
    const float mu = (red1[0] + red1[1] + red1[2] + red1[3]) * (1.0f / HID);

    const float d0 = v.x - mu, d1 = v.y - mu, d2 = v.z - mu, d3 = v.w - mu;
    float ss = d0 * d0 + d1 * d1 + d2 * d2 + d3 * d3;
#pragma unroll
    for (int off = 1; off < 64; off <<= 1) ss += __shfl_xor(ss, off, 64);
    if (lane == 0) red2[wave] = ss;
    __syncthreads();
    const float var = (red2[0] + red2[1] + red2[2] + red2[3]) * (1.0f / HID);
    const float rstd = rsqrtf(var + LNEPS);

    const float4 gv = ((const float4*)g)[threadIdx.x];
    const float4 bv = ((const float4*)be)[threadIdx.x];
    float4 o;
    o.x = d0 * rstd * gv.x + bv.x;
    o.y = d1 * rstd * gv.y + bv.y;
    o.z = d2 * rstd * gv.z + bv.z;
    o.w = d3 * rstd * gv.w + bv.w;
    ((float4*)(out + (size_t)row * HID))[threadIdx.x] = o;
}

// ---------------------------------------------------------------------------
extern "C" void kernel_launch(void* const* d_in, const int* in_sizes, int n_in,
                              void* d_out, int out_size, void* d_ws, size_t ws_size,
                              hipStream_t stream)
{
    const float* X  = (const float*)d_in[0];
    const int* mask = (const int*)d_in[1];
    const float* Wq = (const float*)d_in[2];  const float* bq = (const float*)d_in[3];
    const float* Wk = (const float*)d_in[4];  const float* bk = (const float*)d_in[5];
    const float* Wv = (const float*)d_in[6];  const float* bv = (const float*)d_in[7];
    const float* Wo = (const float*)d_in[8];  const float* bo = (const float*)d_in[9];
    const float* g  = (const float*)d_in[10]; const float* be = (const float*)d_in[11];
    float* out = (float*)d_out;

    char* ws = (char*)d_ws;
    bf16_t* Qb  = (bf16_t*)(ws);                          // [0, 8M)
    bf16_t* Kb  = (bf16_t*)(ws + (8ull  << 20));          // [8M, 16M)
    bf16_t* Vb  = (bf16_t*)(ws + (16ull << 20));          // [16M, 24M)  V^T [bh][d][s]
    bf16_t* Cb  = (bf16_t*)(ws + (24ull << 20));          // [24M, 32M)
    float*  Rb  = (float*)(ws);                           // [0, 16M) aliases dead Q/K
    bf16_t* Xc  = (bf16_t*)(ws + (32ull << 20));          // [32M, 40M)
    bf16_t* Wqc = (bf16_t*)(ws + (40ull << 20));
    bf16_t* Wkc = (bf16_t*)(ws + (42ull << 20));
    bf16_t* Wvc = (bf16_t*)(ws + (44ull << 20));
    bf16_t* Woc = (bf16_t*)(ws + (46ull << 20));

    cvt_kernel <<<dim3(128, 1, 5), 256, 0, stream>>>(X, Wq, Wk, Wv, Wo, Xc, Wqc, Wkc, Wvc, Woc);
    qkv_kernel <<<dim3(8, 32, 3), 256, 0, stream>>>(Xc, Wqc, bq, Wkc, bk, Wvc, bv, Qb, Kb, Vb);
    attn_kernel<<<dim3(32 * 32), 256, 0, stream>>>(Qb, Kb, Vb, mask, Cb);
    oproj_kernel<<<dim3(8, 32), 256, 0, stream>>>(Cb, Woc, bo, X, Rb);
    ln_kernel  <<<MTOT, 256, 0, stream>>>(Rb, g, be, out);
}

// Round 7
// 250.006 us; speedup vs baseline: 1.8292x; 1.2640x over previous
//
#include <hip/hip_runtime.h>
#include <hip/hip_bf16.h>

// Problem: B=2, S=2048, H=1024, HEADS=16, HEAD_DIM=64. Wire dtype fp32; output fp32.
// R7: qkv/oproj GEMMs -> m97 structure: 128x128 tile, BK=32, global_load_lds
// width-16 staging (dense, lane-order = row-major), ds_read_b128 fragments.
// attn (R6 4-wave LDS-tiled version) unchanged.
#define SEQ     2048
#define BATCH   2
#define HID     1024
#define NHEADS  16
#define HD      64
#define MTOT    4096            // BATCH*SEQ
#define LNEPS   1e-6f
#define L2E     1.4426950408889634f
#define SHIFT2  26.0f           // base-2 static softmax shift

typedef __bf16 bf16_t;
typedef bf16_t bf16x8 __attribute__((ext_vector_type(8)));   // 4 VGPRs = one MFMA A/B frag
typedef bf16_t bf16x4 __attribute__((ext_vector_type(4)));   // b64 packed store
typedef float  floatx4 __attribute__((ext_vector_type(4)));  // one MFMA C/D frag

__device__ __forceinline__ floatx4 mfma16(bf16x8 a, bf16x8 b, floatx4 c) {
    return __builtin_amdgcn_mfma_f32_16x16x32_bf16(a, b, c, 0, 0, 0);
}
__device__ __forceinline__ bf16x8 ldg8(const bf16_t* p) { return *(const bf16x8*)p; }

// Stage one 128x32 bf16 tile (rows [0,128), cols [k0,k0+32) of a row-major
// matrix with row_stride elems) into LDS via global_load_lds width 16.
// Wave w stages rows [w*32, (w+1)*32), 2 insts of 16 rows each; LDS dest is
// wave-uniform, HW scatters lane i to dest + i*16 == row-major [16][64B].
__device__ __forceinline__ void stage128x32(const bf16_t* __restrict__ g, int row_stride,
                                            int k0, bf16_t* lds, int wave, int lane)
{
#pragma unroll
    for (int j = 0; j < 2; j++) {
        const int rbase = wave * 32 + j * 16;
        const bf16_t* src = g + (size_t)(rbase + (lane >> 2)) * row_stride + k0 + (lane & 3) * 8;
        bf16_t* dst = lds + rbase * 32;
        __builtin_amdgcn_global_load_lds(
            (const __attribute__((address_space(1))) unsigned int*)src,
            (__attribute__((address_space(3))) unsigned int*)dst, 16, 0, 0);
    }
}

// ---------------------------------------------------------------------------
// Kernel 0: fp32 -> bf16 conversion for X, Wq, Wk, Wv, Wo.
// ---------------------------------------------------------------------------
__global__ __launch_bounds__(256) void cvt_kernel(
    const float* sX, const float* sWq, const float* sWk, const float* sWv, const float* sWo,
    bf16_t* dX, bf16_t* dWq, bf16_t* dWk, bf16_t* dWv, bf16_t* dWo)
{
    const int z = blockIdx.z;
    const float* src; bf16_t* dst; int n;
    switch (z) {
        case 0:  src = sX;  dst = dX;  n = MTOT * HID; break;
        case 1:  src = sWq; dst = dWq; n = HID * HID;  break;
        case 2:  src = sWk; dst = dWk; n = HID * HID;  break;
        case 3:  src = sWv; dst = dWv; n = HID * HID;  break;
        default: src = sWo; dst = dWo; n = HID * HID;  break;
    }
    const int n4 = n >> 2;
    const int stride = gridDim.x * blockDim.x;
    for (int i = blockIdx.x * blockDim.x + threadIdx.x; i < n4; i += stride) {
        const float4 v = ((const float4*)src)[i];
        bf16_t o[4] = {(bf16_t)v.x, (bf16_t)v.y, (bf16_t)v.z, (bf16_t)v.w};
        *(unsigned long long*)(dst + 4 * i) = *(unsigned long long*)o;
    }
}

// ---------------------------------------------------------------------------
// Kernel 1: QKV projection (NT GEMM, m97 structure). Q pre-scaled by 0.125.
// Q,K stored [bh][s][d]; V stored TRANSPOSED [bh][d][s].
// ---------------------------------------------------------------------------
__global__ __launch_bounds__(256) void qkv_kernel(
    const bf16_t* __restrict__ X,
    const bf16_t* __restrict__ Wq, const float* __restrict__ bq,
    const bf16_t* __restrict__ Wk, const float* __restrict__ bk,
    const bf16_t* __restrict__ Wv, const float* __restrict__ bv,
    bf16_t* __restrict__ Qo, bf16_t* __restrict__ Ko, bf16_t* __restrict__ Vo)
{
    const int z = blockIdx.z;
    const bf16_t* W    = (z == 0) ? Wq : (z == 1) ? Wk : Wv;
    const float*  bias = (z == 0) ? bq : (z == 1) ? bk : bv;
    bf16_t*       out  = (z == 0) ? Qo : (z == 1) ? Ko : Vo;

    const int tid  = threadIdx.x;
    const int lane = tid & 63;
    const int wave = tid >> 6;
    const int l16  = lane & 15;
    const int quad = lane >> 4;
    const int m_blk = blockIdx.y * 128;
    const int n_blk = blockIdx.x * 128;
    const int m_w = (wave >> 1) * 64;      // wave offset within tile
    const int n_w = (wave & 1) * 64;

    __shared__ __align__(16) bf16_t As[128 * 32];
    __shared__ __align__(16) bf16_t Bs[128 * 32];

    floatx4 acc[4][4];
#pragma unroll
    for (int i = 0; i < 4; i++)
#pragma unroll
        for (int j = 0; j < 4; j++) acc[i][j] = (floatx4)0.0f;

    for (int k0 = 0; k0 < HID; k0 += 32) {
        __syncthreads();                                   // WAR on tiles
        stage128x32(X + (size_t)m_blk * HID, HID, k0, As, wave, lane);
        stage128x32(W + (size_t)n_blk * HID, HID, k0, Bs, wave, lane);
        __syncthreads();                                   // staging visible

        bf16x8 a[4], b[4];
#pragma unroll
        for (int i = 0; i < 4; i++) a[i] = *(const bf16x8*)&As[(m_w + i * 16 + l16) * 32 + quad * 8];
#pragma unroll
        for (int j = 0; j < 4; j++) b[j] = *(const bf16x8*)&Bs[(n_w + j * 16 + l16) * 32 + quad * 8];
#pragma unroll
        for (int i = 0; i < 4; i++)
#pragma unroll
            for (int j = 0; j < 4; j++) acc[i][j] = mfma16(a[i], b[j], acc[i][j]);
    }

    float bv_[4];
#pragma unroll
    for (int j = 0; j < 4; j++) bv_[j] = bias[n_blk + n_w + j * 16 + l16];
    const float scale = (z == 0) ? 0.125f : 1.0f;   // fold softmax 1/sqrt(64) into Q

#pragma unroll
    for (int i = 0; i < 4; i++) {
#pragma unroll
        for (int j = 0; j < 4; j++) {
            const int n = n_blk + n_w + j * 16 + l16;
            const int h = n >> 6, d = n & 63;
#pragma unroll
            for (int r = 0; r < 4; r++) {
                const int m = m_blk + m_w + i * 16 + quad * 4 + r;  // C: row=quad*4+r, col=l16
                const int bb = m >> 11, s = m & (SEQ - 1);
                const bf16_t val = (bf16_t)((acc[i][j][r] + bv_[j]) * scale);
                if (z == 2)   // V^T: [bh][d][s]
                    out[(((size_t)(bb * NHEADS + h)) * HD + d) * SEQ + s] = val;
                else          // Q/K: [bh][s][d]
                    out[(((size_t)(bb * NHEADS + h)) * SEQ + s) * HD + d] = val;
            }
        }
    }
}

// ---------------------------------------------------------------------------
// Kernel 2: flash attention (R6). Block = 4 waves; wave owns 16 q rows.
// K/V^T tiles staged in LDS; static-shift softmax; zero cross-lane in loop.
// ---------------------------------------------------------------------------
__global__ __launch_bounds__(256, 4) void attn_kernel(
    const bf16_t* __restrict__ Q, const bf16_t* __restrict__ K,
    const bf16_t* __restrict__ Vt, const int* __restrict__ mask,
    bf16_t* __restrict__ ctx)
{
    const int B   = blockIdx.x;            // 0..1023
    const int xcd = B & 7;
    const int idx = B >> 3;                // 0..127
    const int bh  = xcd * 4 + (idx & 3);
    const int q0  = (idx >> 2) * 64;       // block q base
    const int b   = bh >> 4;
    const int h   = bh & 15;
    const int tid  = threadIdx.x;
    const int wave = tid >> 6;
    const int lane = tid & 63;
    const int l16  = lane & 15;
    const int quad = lane >> 4;

    const bf16_t* Qh = Q  + (size_t)bh * SEQ * HD;
    const bf16_t* Kh = K  + (size_t)bh * SEQ * HD;
    const bf16_t* Vh = Vt + (size_t)bh * HD * SEQ;    // [d][s]
    const int*    mk = mask + b * SEQ;

    __shared__ __align__(16) bf16_t Ks[64 * 72];      // K tile  [kv][d]
    __shared__ __align__(16) bf16_t Vs[64 * 72];      // V^T tile [d][kv]
    __shared__ __align__(16) bf16_t Pl[4][16 * 72];   // per-wave P [q][kv]

    bf16_t* Pw = Pl[wave];
    const int qw = q0 + wave * 16;

    bf16x8 bQ[2];
#pragma unroll
    for (int kc = 0; kc < 2; kc++)
        bQ[kc] = ldg8(Qh + (size_t)(qw + l16) * HD + kc * 32 + quad * 8);

    floatx4 O[4];
    floatx4 psum = (floatx4)0.0f;
#pragma unroll
    for (int dt = 0; dt < 4; dt++) O[dt] = (floatx4)0.0f;

    const int r0 = tid >> 3;               // 0..31
    const int c0 = (tid & 7) * 8;          // 0..56

    for (int kt = 0; kt < SEQ; kt += 64) {
        bf16x8 k0v = ldg8(Kh + (size_t)(kt + r0)      * HD + c0);
        bf16x8 k1v = ldg8(Kh + (size_t)(kt + 32 + r0) * HD + c0);
        bf16x8 v0v = ldg8(Vh + (size_t)(r0)      * SEQ + kt + c0);
        bf16x8 v1v = ldg8(Vh + (size_t)(32 + r0) * SEQ + kt + c0);
        int4 mv[4];
#pragma unroll
        for (int kvt = 0; kvt < 4; kvt++)
            mv[kvt] = ((const int4*)(mk + kt + kvt * 16))[quad];

        __syncthreads();
        *(bf16x8*)&Ks[r0 * 72 + c0]        = k0v;
        *(bf16x8*)&Ks[(32 + r0) * 72 + c0] = k1v;
        *(bf16x8*)&Vs[r0 * 72 + c0]        = v0v;
        *(bf16x8*)&Vs[(32 + r0) * 72 + c0] = v1v;
        __syncthreads();

#pragma unroll
        for (int kvt = 0; kvt < 4; kvt++) {
            floatx4 s = (floatx4)0.0f;
#pragma unroll
            for (int kc = 0; kc < 2; kc++) {
                bf16x8 aK = *(const bf16x8*)&Ks[(kvt * 16 + l16) * 72 + kc * 32 + quad * 8];
                s = mfma16(aK, bQ[kc], s);
            }
            const int* mp = (const int*)&mv[kvt];
            floatx4 p;
#pragma unroll
            for (int r = 0; r < 4; r++)
                p[r] = exp2f(fmaf(s[r], L2E, -SHIFT2)) * (float)mp[r];
            bf16x4 pk;
#pragma unroll
            for (int r = 0; r < 4; r++) pk[r] = (bf16_t)p[r];
            *(bf16x4*)&Pw[l16 * 72 + kvt * 16 + quad * 4] = pk;
            psum += p;
        }

        bf16x8 bP[2];
#pragma unroll
        for (int kc = 0; kc < 2; kc++)
            bP[kc] = *(const bf16x8*)&Pw[l16 * 72 + kc * 32 + quad * 8];
#pragma unroll
        for (int dt = 0; dt < 4; dt++)
#pragma unroll
            for (int kc = 0; kc < 2; kc++) {
                bf16x8 aV = *(const bf16x8*)&Vs[(dt * 16 + l16) * 72 + kc * 32 + quad * 8];
                O[dt] = mfma16(aV, bP[kc], O[dt]);
            }
    }

    float su = psum[0] + psum[1] + psum[2] + psum[3];
    su += __shfl_xor(su, 16, 64);
    su += __shfl_xor(su, 32, 64);
    const float linv = (su > 0.0f) ? 1.0f / su : 0.0f;

#pragma unroll
    for (int dt = 0; dt < 4; dt++) {
        floatx4 o = O[dt] * linv;
        bf16x4 pk;
#pragma unroll
        for (int r = 0; r < 4; r++) pk[r] = (bf16_t)o[r];
        *(bf16x4*)&Pw[l16 * 72 + dt * 16 + quad * 4] = pk;
    }
#pragma unroll
    for (int ch = 0; ch < 2; ch++) {
        const int cc  = ch * 64 + lane;
        const int row = cc >> 3;
        const int col = (cc & 7) * 8;
        bf16x8 vv = *(const bf16x8*)&Pw[row * 72 + col];
        *(bf16x8*)&ctx[((size_t)(b * SEQ + qw + row)) * HID + h * 64 + col] = vv;
    }
}

// ---------------------------------------------------------------------------
// Kernel 3: res = ctx @ Wo^T + bo + hidden  -> fp32 (m97 structure)
// ---------------------------------------------------------------------------
__global__ __launch_bounds__(256) void oproj_kernel(
    const bf16_t* __restrict__ C, const bf16_t* __restrict__ Wo,
    const float* __restrict__ bo, const float* __restrict__ X,
    float* __restrict__ res)
{
    const int tid  = threadIdx.x;
    const int lane = tid & 63;
    const int wave = tid >> 6;
    const int l16  = lane & 15;
    const int quad = lane >> 4;
    const int m_blk = blockIdx.y * 128;
    const int n_blk = blockIdx.x * 128;
    const int m_w = (wave >> 1) * 64;
    const int n_w = (wave & 1) * 64;

    __shared__ __align__(16) bf16_t As[128 * 32];
    __shared__ __align__(16) bf16_t Bs[128 * 32];

    floatx4 acc[4][4];
#pragma unroll
    for (int i = 0; i < 4; i++)
#pragma unroll
        for (int j = 0; j < 4; j++) acc[i][j] = (floatx4)0.0f;

    for (int k0 = 0; k0 < HID; k0 += 32) {
        __syncthreads();
        stage128x32(C  + (size_t)m_blk * HID, HID, k0, As, wave, lane);
        stage128x32(Wo + (size_t)n_blk * HID, HID, k0, Bs, wave, lane);
        __syncthreads();

        bf16x8 a[4], b[4];
#pragma unroll
        for (int i = 0; i < 4; i++) a[i] = *(const bf16x8*)&As[(m_w + i * 16 + l16) * 32 + quad * 8];
#pragma unroll
        for (int j = 0; j < 4; j++) b[j] = *(const bf16x8*)&Bs[(n_w + j * 16 + l16) * 32 + quad * 8];
#pragma unroll
        for (int i = 0; i < 4; i++)
#pragma unroll
            for (int j = 0; j < 4; j++) acc[i][j] = mfma16(a[i], b[j], acc[i][j]);
    }

    float bv_[4];
#pragma unroll
    for (int j = 0; j < 4; j++) bv_[j] = bo[n_blk + n_w + j * 16 + l16];

#pragma unroll
    for (int i = 0; i < 4; i++) {
#pragma unroll
        for (int j = 0; j < 4; j++) {
            const int n = n_blk + n_w + j * 16 + l16;
#pragma unroll
            for (int r = 0; r < 4; r++) {
                const int m = m_blk + m_w + i * 16 + quad * 4 + r;
                res[(size_t)m * HID + n] = acc[i][j][r] + bv_[j] + X[(size_t)m * HID + n];
            }
        }
    }
}

// ---------------------------------------------------------------------------
// Kernel 4: LayerNorm over rows of 1024 fp32 -> fp32 out
// ---------------------------------------------------------------------------
__global__ __launch_bounds__(256) void ln_kernel(
    const float* __restrict__ res, const float* __restrict__ g,
    const float* __restrict__ be, float* __restrict__ out)
{
    __shared__ float red1[4], red2[4];
    const int row  = blockIdx.x;
    const int lane = threadIdx.x & 63;
    const int wave = threadIdx.x >> 6;
    const float4 v = ((const float4*)(res + (size_t)row * HID))[threadIdx.x];

    float s = v.x + v.y + v.z + v.w;
#pragma unroll
    for (int off = 1; off < 64; off <<= 1) s += __shfl_xor(s, off, 64);
    if (lane == 0) red1[wave] = s;
    __syncthreads();
    const float mu = (red1[0] + red1[1] + red1[2] + red1[3]) * (1.0f / HID);

    const float d0 = v.x - mu, d1 = v.y - mu, d2 = v.z - mu, d3 = v.w - mu;
    float ss = d0 * d0 + d1 * d1 + d2 * d2 + d3 * d3;
#pragma unroll
    for (int off = 1; off < 64; off <<= 1) ss += __shfl_xor(ss, off, 64);
    if (lane == 0) red2[wave] = ss;
    __syncthreads();
    const float var = (red2[0] + red2[1] + red2[2] + red2[3]) * (1.0f / HID);
    const float rstd = rsqrtf(var + LNEPS);

    const float4 gv = ((const float4*)g)[threadIdx.x];
    const float4 bv = ((const float4*)be)[threadIdx.x];
    float4 o;
    o.x = d0 * rstd * gv.x + bv.x;
    o.y = d1 * rstd * gv.y + bv.y;
    o.z = d2 * rstd * gv.z + bv.z;
    o.w = d3 * rstd * gv.w + bv.w;
    ((float4*)(out + (size_t)row * HID))[threadIdx.x] = o;
}

// ---------------------------------------------------------------------------
extern "C" void kernel_launch(void* const* d_in, const int* in_sizes, int n_in,
                              void* d_out, int out_size, void* d_ws, size_t ws_size,
                              hipStream_t stream)
{
    const float* X  = (const float*)d_in[0];
    const int* mask = (const int*)d_in[1];
    const float* Wq = (const float*)d_in[2];  const float* bq = (const float*)d_in[3];
    const float* Wk = (const float*)d_in[4];  const float* bk = (const float*)d_in[5];
    const float* Wv = (const float*)d_in[6];  const float* bv = (const float*)d_in[7];
    const float* Wo = (const float*)d_in[8];  const float* bo = (const float*)d_in[9];
    const float* g  = (const float*)d_in[10]; const float* be = (const float*)d_in[11];
    float* out = (float*)d_out;

    char* ws = (char*)d_ws;
    bf16_t* Qb  = (bf16_t*)(ws);                          // [0, 8M)
    bf16_t* Kb  = (bf16_t*)(ws + (8ull  << 20));          // [8M, 16M)
    bf16_t* Vb  = (bf16_t*)(ws + (16ull << 20));          // [16M, 24M)  V^T [bh][d][s]
    bf16_t* Cb  = (bf16_t*)(ws + (24ull << 20));          // [24M, 32M)
    float*  Rb  = (float*)(ws);                           // [0, 16M) aliases dead Q/K
    bf16_t* Xc  = (bf16_t*)(ws + (32ull << 20));          // [32M, 40M)
    bf16_t* Wqc = (bf16_t*)(ws + (40ull << 20));
    bf16_t* Wkc = (bf16_t*)(ws + (42ull << 20));
    bf16_t* Wvc = (bf16_t*)(ws + (44ull << 20));
    bf16_t* Woc = (bf16_t*)(ws + (46ull << 20));

    cvt_kernel <<<dim3(128, 1, 5), 256, 0, stream>>>(X, Wq, Wk, Wv, Wo, Xc, Wqc, Wkc, Wvc, Woc);
    qkv_kernel <<<dim3(8, 32, 3), 256, 0, stream>>>(Xc, Wqc, bq, Wkc, bk, Wvc, bv, Qb, Kb, Vb);
    attn_kernel<<<dim3(32 * 32), 256, 0, stream>>>(Qb, Kb, Vb, mask, Cb);
    oproj_kernel<<<dim3(8, 32), 256, 0, stream>>>(Cb, Woc, bo, X, Rb);
    ln_kernel  <<<MTOT, 256, 0, stream>>>(Rb, g, be, out);
}

// Round 9
// 247.014 us; speedup vs baseline: 1.8514x; 1.0121x over previous
//
#include <hip/hip_runtime.h>
#include <hip/hip_bf16.h>

// Problem: B=2, S=2048, H=1024, HEADS=16, HEAD_DIM=64. Wire dtype fp32; output fp32.
// R9 = R8 with the oproj epilogue coverage bug fixed (store loop previously
// wrote only 64 of 256 float4s per chunk -> 3/4 of res stayed poisoned).
// qkv: LDS-transposed Q/K stores + packed b64 V^T stores. Residual in ln.
#define SEQ     2048
#define BATCH   2
#define HID     1024
#define NHEADS  16
#define HD      64
#define MTOT    4096            // BATCH*SEQ
#define LNEPS   1e-6f
#define L2E     1.4426950408889634f
#define SHIFT2  26.0f           // base-2 static softmax shift

typedef __bf16 bf16_t;
typedef bf16_t bf16x8 __attribute__((ext_vector_type(8)));   // 4 VGPRs = one MFMA A/B frag
typedef bf16_t bf16x4 __attribute__((ext_vector_type(4)));   // b64 packed store
typedef float  floatx4 __attribute__((ext_vector_type(4)));  // one MFMA C/D frag

__device__ __forceinline__ floatx4 mfma16(bf16x8 a, bf16x8 b, floatx4 c) {
    return __builtin_amdgcn_mfma_f32_16x16x32_bf16(a, b, c, 0, 0, 0);
}
__device__ __forceinline__ bf16x8 ldg8(const bf16_t* p) { return *(const bf16x8*)p; }

// Stage one 128x32 bf16 tile (rows [0,128), cols [k0,k0+32) of a row-major
// matrix, row_stride elems) into LDS via global_load_lds width 16.
__device__ __forceinline__ void stage128x32(const bf16_t* __restrict__ g, int row_stride,
                                            int k0, bf16_t* lds, int wave, int lane)
{
#pragma unroll
    for (int j = 0; j < 2; j++) {
        const int rbase = wave * 32 + j * 16;
        const bf16_t* src = g + (size_t)(rbase + (lane >> 2)) * row_stride + k0 + (lane & 3) * 8;
        bf16_t* dst = lds + rbase * 32;
        __builtin_amdgcn_global_load_lds(
            (const __attribute__((address_space(1))) unsigned int*)src,
            (__attribute__((address_space(3))) unsigned int*)dst, 16, 0, 0);
    }
}

// ---------------------------------------------------------------------------
// Kernel 0: fp32 -> bf16 conversion for X, Wq, Wk, Wv, Wo.
// ---------------------------------------------------------------------------
__global__ __launch_bounds__(256) void cvt_kernel(
    const float* sX, const float* sWq, const float* sWk, const float* sWv, const float* sWo,
    bf16_t* dX, bf16_t* dWq, bf16_t* dWk, bf16_t* dWv, bf16_t* dWo)
{
    const int z = blockIdx.z;
    const float* src; bf16_t* dst; int n;
    switch (z) {
        case 0:  src = sX;  dst = dX;  n = MTOT * HID; break;
        case 1:  src = sWq; dst = dWq; n = HID * HID;  break;
        case 2:  src = sWk; dst = dWk; n = HID * HID;  break;
        case 3:  src = sWv; dst = dWv; n = HID * HID;  break;
        default: src = sWo; dst = dWo; n = HID * HID;  break;
    }
    const int n4 = n >> 2;
    const int stride = gridDim.x * blockDim.x;
    for (int i = blockIdx.x * blockDim.x + threadIdx.x; i < n4; i += stride) {
        const float4 v = ((const float4*)src)[i];
        bf16_t o[4] = {(bf16_t)v.x, (bf16_t)v.y, (bf16_t)v.z, (bf16_t)v.w};
        *(unsigned long long*)(dst + 4 * i) = *(unsigned long long*)o;
    }
}

// ---------------------------------------------------------------------------
// Kernel 1: QKV projection (NT GEMM, m97 staging). Q pre-scaled by 0.125.
// Q,K stored [bh][s][d] via LDS-transposed coalesced stores; V stored
// TRANSPOSED [bh][d][s] via packed b64 (s-consecutive per lane).
// ---------------------------------------------------------------------------
__global__ __launch_bounds__(256) void qkv_kernel(
    const bf16_t* __restrict__ X,
    const bf16_t* __restrict__ Wq, const float* __restrict__ bq,
    const bf16_t* __restrict__ Wk, const float* __restrict__ bk,
    const bf16_t* __restrict__ Wv, const float* __restrict__ bv,
    bf16_t* __restrict__ Qo, bf16_t* __restrict__ Ko, bf16_t* __restrict__ Vo)
{
    const int z = blockIdx.z;
    const bf16_t* W    = (z == 0) ? Wq : (z == 1) ? Wk : Wv;
    const float*  bias = (z == 0) ? bq : (z == 1) ? bk : bv;
    bf16_t*       out  = (z == 0) ? Qo : (z == 1) ? Ko : Vo;

    const int tid  = threadIdx.x;
    const int lane = tid & 63;
    const int wave = tid >> 6;
    const int l16  = lane & 15;
    const int quad = lane >> 4;
    const int m_blk = blockIdx.y * 128;
    const int n_blk = blockIdx.x * 128;
    const int m_w = (wave >> 1) * 64;
    const int n_w = (wave & 1) * 64;

    // union: K-loop staging (As 8192 B + Bs 8192 B) / epilogue transpose (4x4608 B)
    __shared__ __align__(16) char smem[18432];
    bf16_t* As = (bf16_t*)smem;
    bf16_t* Bs = (bf16_t*)(smem + 8192);

    floatx4 acc[4][4];
#pragma unroll
    for (int i = 0; i < 4; i++)
#pragma unroll
        for (int j = 0; j < 4; j++) acc[i][j] = (floatx4)0.0f;

    for (int k0 = 0; k0 < HID; k0 += 32) {
        __syncthreads();                                   // WAR on tiles
        stage128x32(X + (size_t)m_blk * HID, HID, k0, As, wave, lane);
        stage128x32(W + (size_t)n_blk * HID, HID, k0, Bs, wave, lane);
        __syncthreads();                                   // staging visible

        bf16x8 a[4], b[4];
#pragma unroll
        for (int i = 0; i < 4; i++) a[i] = *(const bf16x8*)&As[(m_w + i * 16 + l16) * 32 + quad * 8];
#pragma unroll
        for (int j = 0; j < 4; j++) b[j] = *(const bf16x8*)&Bs[(n_w + j * 16 + l16) * 32 + quad * 8];
#pragma unroll
        for (int i = 0; i < 4; i++)
#pragma unroll
            for (int j = 0; j < 4; j++) acc[i][j] = mfma16(a[i], b[j], acc[i][j]);
    }
    __syncthreads();                                       // all frag reads done; smem reusable

    float bv_[4];
#pragma unroll
    for (int j = 0; j < 4; j++) bv_[j] = bias[n_blk + n_w + j * 16 + l16];

    if (z != 2) {
        // Q/K [bh][s][d]: per-wave LDS transpose (32-row chunks, stride 72) ->
        // coalesced b128 stores.
        const float scale = (z == 0) ? 0.125f : 1.0f;
        bf16_t* Tw = (bf16_t*)(smem + wave * 4608);        // 32*72 = 2304 elems
        const int hN = (n_blk + n_w) >> 6;                 // head (n_w 64-aligned)
#pragma unroll
        for (int ih = 0; ih < 2; ih++) {
#pragma unroll
            for (int i2 = 0; i2 < 2; i2++) {
                const int i = ih * 2 + i2;
#pragma unroll
                for (int j = 0; j < 4; j++)
#pragma unroll
                    for (int r = 0; r < 4; r++)
                        Tw[(i2 * 16 + quad * 4 + r) * 72 + j * 16 + l16] =
                            (bf16_t)((acc[i][j][r] + bv_[j]) * scale);
            }
#pragma unroll
            for (int p = 0; p < 4; p++) {
                const int srow = p * 8 + (lane >> 3);      // 0..31
                const int col  = (lane & 7) * 8;           // 0..56
                bf16x8 v = *(const bf16x8*)&Tw[srow * 72 + col];
                const int m = m_blk + m_w + ih * 32 + srow;
                const int bb = m >> 11, s = m & (SEQ - 1);
                *(bf16x8*)&out[(((size_t)(bb * NHEADS + hN)) * SEQ + s) * HD + col] = v;
            }
        }
    } else {
        // V^T [bh][d][s]: acc r-values are s-consecutive -> packed b64 stores.
#pragma unroll
        for (int i = 0; i < 4; i++) {
            const int m = m_blk + m_w + i * 16 + quad * 4;
            const int bb = m >> 11, s = m & (SEQ - 1);
#pragma unroll
            for (int j = 0; j < 4; j++) {
                const int n = n_blk + n_w + j * 16 + l16;
                const int h = n >> 6, d = n & 63;
                bf16x4 pk;
#pragma unroll
                for (int r = 0; r < 4; r++) pk[r] = (bf16_t)(acc[i][j][r] + bv_[j]);
                *(bf16x4*)&out[(((size_t)(bb * NHEADS + h)) * HD + d) * SEQ + s] = pk;
            }
        }
    }
}

// ---------------------------------------------------------------------------
// Kernel 2: flash attention (unchanged R7). 4 waves, 16 q/wave, kv tile 64,
// LDS-staged K/V^T, static-shift softmax, zero cross-lane in loop.
// ---------------------------------------------------------------------------
__global__ __launch_bounds__(256, 4) void attn_kernel(
    const bf16_t* __restrict__ Q, const bf16_t* __restrict__ K,
    const bf16_t* __restrict__ Vt, const int* __restrict__ mask,
    bf16_t* __restrict__ ctx)
{
    const int B   = blockIdx.x;            // 0..1023
    const int xcd = B & 7;
    const int idx = B >> 3;                // 0..127
    const int bh  = xcd * 4 + (idx & 3);
    const int q0  = (idx >> 2) * 64;       // block q base
    const int b   = bh >> 4;
    const int h   = bh & 15;
    const int tid  = threadIdx.x;
    const int wave = tid >> 6;
    const int lane = tid & 63;
    const int l16  = lane & 15;
    const int quad = lane >> 4;

    const bf16_t* Qh = Q  + (size_t)bh * SEQ * HD;
    const bf16_t* Kh = K  + (size_t)bh * SEQ * HD;
    const bf16_t* Vh = Vt + (size_t)bh * HD * SEQ;    // [d][s]
    const int*    mk = mask + b * SEQ;

    __shared__ __align__(16) bf16_t Ks[64 * 72];      // K tile  [kv][d]
    __shared__ __align__(16) bf16_t Vs[64 * 72];      // V^T tile [d][kv]
    __shared__ __align__(16) bf16_t Pl[4][16 * 72];   // per-wave P [q][kv]

    bf16_t* Pw = Pl[wave];
    const int qw = q0 + wave * 16;

    bf16x8 bQ[2];
#pragma unroll
    for (int kc = 0; kc < 2; kc++)
        bQ[kc] = ldg8(Qh + (size_t)(qw + l16) * HD + kc * 32 + quad * 8);

    floatx4 O[4];
    floatx4 psum = (floatx4)0.0f;
#pragma unroll
    for (int dt = 0; dt < 4; dt++) O[dt] = (floatx4)0.0f;

    const int r0 = tid >> 3;               // 0..31
    const int c0 = (tid & 7) * 8;          // 0..56

    for (int kt = 0; kt < SEQ; kt += 64) {
        bf16x8 k0v = ldg8(Kh + (size_t)(kt + r0)      * HD + c0);
        bf16x8 k1v = ldg8(Kh + (size_t)(kt + 32 + r0) * HD + c0);
        bf16x8 v0v = ldg8(Vh + (size_t)(r0)      * SEQ + kt + c0);
        bf16x8 v1v = ldg8(Vh + (size_t)(32 + r0) * SEQ + kt + c0);
        int4 mv[4];
#pragma unroll
        for (int kvt = 0; kvt < 4; kvt++)
            mv[kvt] = ((const int4*)(mk + kt + kvt * 16))[quad];

        __syncthreads();
        *(bf16x8*)&Ks[r0 * 72 + c0]        = k0v;
        *(bf16x8*)&Ks[(32 + r0) * 72 + c0] = k1v;
        *(bf16x8*)&Vs[r0 * 72 + c0]        = v0v;
        *(bf16x8*)&Vs[(32 + r0) * 72 + c0] = v1v;
        __syncthreads();

#pragma unroll
        for (int kvt = 0; kvt < 4; kvt++) {
            floatx4 s = (floatx4)0.0f;
#pragma unroll
            for (int kc = 0; kc < 2; kc++) {
                bf16x8 aK = *(const bf16x8*)&Ks[(kvt * 16 + l16) * 72 + kc * 32 + quad * 8];
                s = mfma16(aK, bQ[kc], s);
            }
            const int* mp = (const int*)&mv[kvt];
            floatx4 p;
#pragma unroll
            for (int r = 0; r < 4; r++)
                p[r] = exp2f(fmaf(s[r], L2E, -SHIFT2)) * (float)mp[r];
            bf16x4 pk;
#pragma unroll
            for (int r = 0; r < 4; r++) pk[r] = (bf16_t)p[r];
            *(bf16x4*)&Pw[l16 * 72 + kvt * 16 + quad * 4] = pk;
            psum += p;
        }

        bf16x8 bP[2];
#pragma unroll
        for (int kc = 0; kc < 2; kc++)
            bP[kc] = *(const bf16x8*)&Pw[l16 * 72 + kc * 32 + quad * 8];
#pragma unroll
        for (int dt = 0; dt < 4; dt++)
#pragma unroll
            for (int kc = 0; kc < 2; kc++) {
                bf16x8 aV = *(const bf16x8*)&Vs[(dt * 16 + l16) * 72 + kc * 32 + quad * 8];
                O[dt] = mfma16(aV, bP[kc], O[dt]);
            }
    }

    float su = psum[0] + psum[1] + psum[2] + psum[3];
    su += __shfl_xor(su, 16, 64);
    su += __shfl_xor(su, 32, 64);
    const float linv = (su > 0.0f) ? 1.0f / su : 0.0f;

#pragma unroll
    for (int dt = 0; dt < 4; dt++) {
        floatx4 o = O[dt] * linv;
        bf16x4 pk;
#pragma unroll
        for (int r = 0; r < 4; r++) pk[r] = (bf16_t)o[r];
        *(bf16x4*)&Pw[l16 * 72 + dt * 16 + quad * 4] = pk;
    }
#pragma unroll
    for (int ch = 0; ch < 2; ch++) {
        const int cc  = ch * 64 + lane;
        const int row = cc >> 3;
        const int col = (cc & 7) * 8;
        bf16x8 vv = *(const bf16x8*)&Pw[row * 72 + col];
        *(bf16x8*)&ctx[((size_t)(b * SEQ + qw + row)) * HID + h * 64 + col] = vv;
    }
}

// ---------------------------------------------------------------------------
// Kernel 3: res = ctx @ Wo^T + bo  (residual added in ln_kernel) -> fp32
// m97 staging + fp32 LDS-transpose epilogue (full 256-float4 coverage).
// ---------------------------------------------------------------------------
__global__ __launch_bounds__(256) void oproj_kernel(
    const bf16_t* __restrict__ C, const bf16_t* __restrict__ Wo,
    const float* __restrict__ bo, float* __restrict__ res)
{
    const int tid  = threadIdx.x;
    const int lane = tid & 63;
    const int wave = tid >> 6;
    const int l16  = lane & 15;
    const int quad = lane >> 4;
    const int m_blk = blockIdx.y * 128;
    const int n_blk = blockIdx.x * 128;
    const int m_w = (wave >> 1) * 64;
    const int n_w = (wave & 1) * 64;

    // union: staging (16384 B) / fp32 transpose (4 x 4352 B)
    __shared__ __align__(16) char smem[17408];
    bf16_t* As = (bf16_t*)smem;
    bf16_t* Bs = (bf16_t*)(smem + 8192);

    floatx4 acc[4][4];
#pragma unroll
    for (int i = 0; i < 4; i++)
#pragma unroll
        for (int j = 0; j < 4; j++) acc[i][j] = (floatx4)0.0f;

    for (int k0 = 0; k0 < HID; k0 += 32) {
        __syncthreads();
        stage128x32(C  + (size_t)m_blk * HID, HID, k0, As, wave, lane);
        stage128x32(Wo + (size_t)n_blk * HID, HID, k0, Bs, wave, lane);
        __syncthreads();

        bf16x8 a[4], b[4];
#pragma unroll
        for (int i = 0; i < 4; i++) a[i] = *(const bf16x8*)&As[(m_w + i * 16 + l16) * 32 + quad * 8];
#pragma unroll
        for (int j = 0; j < 4; j++) b[j] = *(const bf16x8*)&Bs[(n_w + j * 16 + l16) * 32 + quad * 8];
#pragma unroll
        for (int i = 0; i < 4; i++)
#pragma unroll
            for (int j = 0; j < 4; j++) acc[i][j] = mfma16(a[i], b[j], acc[i][j]);
    }
    __syncthreads();                                       // smem reusable

    float bv_[4];
#pragma unroll
    for (int j = 0; j < 4; j++) bv_[j] = bo[n_blk + n_w + j * 16 + l16];

    float* Tw = (float*)(smem + wave * 4352);              // 16 x 68 fp32
#pragma unroll
    for (int ch = 0; ch < 4; ch++) {
#pragma unroll
        for (int j = 0; j < 4; j++)
#pragma unroll
            for (int r = 0; r < 4; r++)
                Tw[(quad * 4 + r) * 68 + j * 16 + l16] = acc[ch][j][r] + bv_[j];
        // full coverage: 256 float4s = 4 per lane (R8 bug: only 64 stored)
#pragma unroll
        for (int cc = 0; cc < 4; cc++) {
            const int idx = cc * 64 + lane;                // 0..255
            const int row = idx >> 4;                      // 0..15
            const int col = (idx & 15) * 4;                // 0..60
            float4 v = *(const float4*)&Tw[row * 68 + col];
            const int m = m_blk + m_w + ch * 16 + row;
            *(float4*)&res[(size_t)m * HID + n_blk + n_w + col] = v;
        }
    }
}

// ---------------------------------------------------------------------------
// Kernel 4: LayerNorm((res + X)) over rows of 1024 -> fp32 out
// ---------------------------------------------------------------------------
__global__ __launch_bounds__(256) void ln_kernel(
    const float* __restrict__ res, const float* __restrict__ X,
    const float* __restrict__ g, const float* __restrict__ be,
    float* __restrict__ out)
{
    __shared__ float red1[4], red2[4];
    const int row  = blockIdx.x;
    const int lane = threadIdx.x & 63;
    const int wave = threadIdx.x >> 6;
    const float4 a = ((const float4*)(res + (size_t)row * HID))[threadIdx.x];
    const float4 x = ((const float4*)(X   + (size_t)row * HID))[threadIdx.x];
    float4 v;
    v.x = a.x + x.x; v.y = a.y + x.y; v.z = a.z + x.z; v.w = a.w + x.w;

    float s = v.x + v.y + v.z + v.w;
#pragma unroll
    for (int off = 1; off < 64; off <<= 1) s += __shfl_xor(s, off, 64);
    if (lane == 0) red1[wave] = s;
    __syncthreads();
    const float mu = (red1[0] + red1[1] + red1[2] + red1[3]) * (1.0f / HID);

    const float d0 = v.x - mu, d1 = v.y - mu, d2 = v.z - mu, d3 = v.w - mu;
    float ss = d0 * d0 + d1 * d1 + d2 * d2 + d3 * d3;
#pragma unroll
    for (int off = 1; off < 64; off <<= 1) ss += __shfl_xor(ss, off, 64);
    if (lane == 0) red2[wave] = ss;
    __syncthreads();
    const float var = (red2[0] + red2[1] + red2[2] + red2[3]) * (1.0f / HID);
    const float rstd = rsqrtf(var + LNEPS);

    const float4 gv = ((const float4*)g)[threadIdx.x];
    const float4 bv = ((const float4*)be)[threadIdx.x];
    float4 o;
    o.x = d0 * rstd * gv.x + bv.x;
    o.y = d1 * rstd * gv.y + bv.y;
    o.z = d2 * rstd * gv.z + bv.z;
    o.w = d3 * rstd * gv.w + bv.w;
    ((float4*)(out + (size_t)row * HID))[threadIdx.x] = o;
}

// ---------------------------------------------------------------------------
extern "C" void kernel_launch(void* const* d_in, const int* in_sizes, int n_in,
                              void* d_out, int out_size, void* d_ws, size_t ws_size,
                              hipStream_t stream)
{
    const float* X  = (const float*)d_in[0];
    const int* mask = (const int*)d_in[1];
    const float* Wq = (const float*)d_in[2];  const float* bq = (const float*)d_in[3];
    const float* Wk = (const float*)d_in[4];  const float* bk = (const float*)d_in[5];
    const float* Wv = (const float*)d_in[6];  const float* bv = (const float*)d_in[7];
    const float* Wo = (const float*)d_in[8];  const float* bo = (const float*)d_in[9];
    const float* g  = (const float*)d_in[10]; const float* be = (const float*)d_in[11];
    float* out = (float*)d_out;

    char* ws = (char*)d_ws;
    bf16_t* Qb  = (bf16_t*)(ws);                          // [0, 8M)
    bf16_t* Kb  = (bf16_t*)(ws + (8ull  << 20));          // [8M, 16M)
    bf16_t* Vb  = (bf16_t*)(ws + (16ull << 20));          // [16M, 24M)  V^T [bh][d][s]
    bf16_t* Cb  = (bf16_t*)(ws + (24ull << 20));          // [24M, 32M)
    float*  Rb  = (float*)(ws);                           // [0, 16M) aliases dead Q/K
    bf16_t* Xc  = (bf16_t*)(ws + (32ull << 20));          // [32M, 40M)
    bf16_t* Wqc = (bf16_t*)(ws + (40ull << 20));
    bf16_t* Wkc = (bf16_t*)(ws + (42ull << 20));
    bf16_t* Wvc = (bf16_t*)(ws + (44ull << 20));
    bf16_t* Woc = (bf16_t*)(ws + (46ull << 20));

    cvt_kernel <<<dim3(128, 1, 5), 256, 0, stream>>>(X, Wq, Wk, Wv, Wo, Xc, Wqc, Wkc, Wvc, Woc);
    qkv_kernel <<<dim3(8, 32, 3), 256, 0, stream>>>(Xc, Wqc, bq, Wkc, bk, Wvc, bv, Qb, Kb, Vb);
    attn_kernel<<<dim3(32 * 32), 256, 0, stream>>>(Qb, Kb, Vb, mask, Cb);
    oproj_kernel<<<dim3(8, 32), 256, 0, stream>>>(Cb, Woc, bo, Rb);
    ln_kernel  <<<MTOT, 256, 0, stream>>>(Rb, X, g, be, out);
}